// Round 8
// baseline (242.903 us; speedup 1.0000x reference)
//
#include <hip/hip_runtime.h>
#include <hip/hip_bf16.h>

#define N_NODES 50000
#define N_EDGES 800000
#define DIM_IN 64
#define DIM_H 32
#define HEADS 4
#define NCLS 10
#define NEG 0.2f
#define NBUCK 196  // ceil(50000/256) buckets of 256 dst nodes

// ---------------- CSR build (binned, single-writer adj regions) ----------------

__global__ void k_bhist(const int* __restrict__ dst, int* __restrict__ bh) {
    __shared__ int lh[NBUCK];
    for (int i = threadIdx.x; i < NBUCK; i += 256) lh[i] = 0;
    __syncthreads();
    int base = blockIdx.x * 1024 + threadIdx.x;
#pragma unroll
    for (int r = 0; r < 4; r++) {
        int e = base + r * 256;
        if (e < N_EDGES) atomicAdd(&lh[dst[e] >> 8], 1);
    }
    __syncthreads();
    for (int i = threadIdx.x; i < NBUCK; i += 256) {
        int c = lh[i];
        if (c) atomicAdd(&bh[i], c);
    }
}

__global__ void k_bscan(const int* __restrict__ bh, int* __restrict__ bbase,
                        int* __restrict__ gcur) {
    __shared__ int s[256];
    int t = threadIdx.x;
    int v = (t < NBUCK) ? bh[t] : 0;
    s[t] = v;
    __syncthreads();
    for (int off = 1; off < 256; off <<= 1) {
        int u = (t >= off) ? s[t - off] : 0;
        __syncthreads();
        s[t] += u;
        __syncthreads();
    }
    int excl = s[t] - v;
    if (t < NBUCK) {
        bbase[t] = excl;
        gcur[t] = excl;
    }
    if (t == 0) bbase[NBUCK] = N_EDGES;
}

__global__ void k_bin(const int* __restrict__ src, const int* __restrict__ dst,
                      int* __restrict__ gcur, unsigned* __restrict__ stage) {
    __shared__ int lh[NBUCK], chunk[NBUCK];
    int t = threadIdx.x;
    for (int i = t; i < NBUCK; i += 256) lh[i] = 0;
    __syncthreads();
    int e0 = blockIdx.x * 4096;
    unsigned pk[16];
    int bk[16];
#pragma unroll
    for (int r = 0; r < 16; r++) {
        int e = e0 + r * 256 + t;
        bool ok = e < N_EDGES;
        int s = ok ? src[e] : 0;
        int d = ok ? dst[e] : 0;
        bk[r] = ok ? (d >> 8) : -1;
        pk[r] = (unsigned)s | ((unsigned)(d & 255) << 16);
        if (ok) atomicAdd(&lh[bk[r]], 1);
    }
    __syncthreads();
    for (int i = t; i < NBUCK; i += 256) {
        int c = lh[i];
        chunk[i] = c ? atomicAdd(&gcur[i], c) : 0;
        lh[i] = 0;  // reuse as local cursor
    }
    __syncthreads();
#pragma unroll
    for (int r = 0; r < 16; r++) {
        if (bk[r] >= 0) {
            int lp = atomicAdd(&lh[bk[r]], 1);
            stage[chunk[bk[r]] + lp] = pk[r];
        }
    }
}

__global__ void k_csr(const unsigned* __restrict__ stage, const int* __restrict__ bbase,
                      int* __restrict__ row, int* __restrict__ adj) {
    __shared__ int lcnt[256], lcur[256], sc[256];
    int b = blockIdx.x, t = threadIdx.x;
    int s0 = bbase[b], s1 = bbase[b + 1];
    lcnt[t] = 0;
    __syncthreads();
    for (int i = s0 + t; i < s1; i += 256) atomicAdd(&lcnt[stage[i] >> 16], 1);
    __syncthreads();
    int v = lcnt[t];
    sc[t] = v;
    __syncthreads();
    for (int off = 1; off < 256; off <<= 1) {
        int u = (t >= off) ? sc[t - off] : 0;
        __syncthreads();
        sc[t] += u;
        __syncthreads();
    }
    int excl = sc[t] - v;
    int n = b * 256 + t;
    if (n < N_NODES) row[n] = s0 + excl;
    if (b == NBUCK - 1 && t == 0) row[N_NODES] = N_EDGES;
    lcur[t] = s0 + excl;
    __syncthreads();
    for (int i = s0 + t; i < s1; i += 256) {
        unsigned p = stage[i];
        int pos = atomicAdd(&lcur[p >> 16], 1);
        adj[pos] = (int)(p & 0xFFFFu);
    }
}

// ---------------- helpers ----------------

__device__ __forceinline__ unsigned short f2bf(float v) {  // RTN f32->bf16
    unsigned u = __builtin_bit_cast(unsigned, v);
    u += 0x7FFFu + ((u >> 16) & 1u);
    return (unsigned short)(u >> 16);
}
__device__ __forceinline__ float bf2f(unsigned short h) {
    return __builtin_bit_cast(float, (unsigned)h << 16);
}

// ---------------- combined layer-1 weights ----------------
// No nonlinearity between embed and layer-1 proj:
// fs1|fd1 = gf @ Wc + bc, Wc = W_in@[W1s|W1d] (64x256),
// bc = b_in@[W1s|W1d] + [b1s|b1d].
__global__ void k_wcomb(const float* __restrict__ W_in, const float* __restrict__ b_in,
                        const float* __restrict__ W1s, const float* __restrict__ b1s,
                        const float* __restrict__ W1d, const float* __restrict__ b1d,
                        float* __restrict__ Wc, float* __restrict__ bc) {
    int g = blockIdx.x * 256 + threadIdx.x;  // [0, 64*256)
    int i = g >> 8, j = g & 255;
    const float* col = (j < 128) ? &W1s[j] : &W1d[j - 128];
    float s = 0.f;
#pragma unroll
    for (int k = 0; k < 32; k++) s += W_in[i * 32 + k] * col[k * 128];
    Wc[g] = s;
    if (i == 0) {
        float sb = (j < 128) ? b1s[j] : b1d[j - 128];
#pragma unroll
        for (int k = 0; k < 32; k++) sb += b_in[k] * col[k * 128];
        bc[j] = sb;
    }
}

// ---------------- layer-1 fused projection ----------------
// [50000x64]@[64x256] from gf. One wave per 8 nodes; two passes (fs cols,
// fd cols). Lane l: col group c4=l&31, K-half h=l>>5; w[32] float4 (128 VGPR
// per pass); halves combined via shfl_xor(32).
__global__ __launch_bounds__(256, 1) void k_proj1(
    const float* __restrict__ gf, const float* __restrict__ Wc,
    const float* __restrict__ bc, unsigned short* __restrict__ fsh,
    float* __restrict__ fd) {
    int lane = threadIdx.x & 63;
    int wave = (blockIdx.x * 256 + threadIdx.x) >> 6;
    int c4 = lane & 31, h = lane >> 5;
    int n0 = wave * 8;
#pragma unroll 1
    for (int pass = 0; pass < 2; ++pass) {
        int cbase = pass * 128 + c4 * 4;
        float4 w[32];
#pragma unroll
        for (int k = 0; k < 32; k++)
            w[k] = *(const float4*)&Wc[(size_t)(h * 32 + k) * 256 + cbase];
        float4 bias = *(const float4*)&bc[cbase];
#pragma unroll 2
        for (int i = 0; i < 8; i++) {
            int n = n0 + i;
            if (n >= N_NODES) break;
            int nu = __builtin_amdgcn_readfirstlane(n);
            const float4* xr = (const float4*)(gf + (size_t)nu * DIM_IN + h * 32);
            float4 acc = {0.f, 0.f, 0.f, 0.f};
#pragma unroll
            for (int k4 = 0; k4 < 8; k4++) {
                float4 xv = xr[k4];
#pragma unroll
                for (int j = 0; j < 4; j++) {
                    float xk = (j == 0) ? xv.x : (j == 1) ? xv.y : (j == 2) ? xv.z : xv.w;
                    float4 wk = w[k4 * 4 + j];
                    acc.x += xk * wk.x;
                    acc.y += xk * wk.y;
                    acc.z += xk * wk.z;
                    acc.w += xk * wk.w;
                }
            }
            acc.x += __shfl_xor(acc.x, 32, 64);
            acc.y += __shfl_xor(acc.y, 32, 64);
            acc.z += __shfl_xor(acc.z, 32, 64);
            acc.w += __shfl_xor(acc.w, 32, 64);
            if (lane < 32) {
                acc.x += bias.x;
                acc.y += bias.y;
                acc.z += bias.z;
                acc.w += bias.w;
                if (pass == 0) {
                    ushort4 o;
                    o.x = f2bf(acc.x);
                    o.y = f2bf(acc.y);
                    o.z = f2bf(acc.z);
                    o.w = f2bf(acc.w);
                    *(ushort4*)&fsh[(size_t)nu * 128 + c4 * 4] = o;
                } else {
                    *(float4*)&fd[(size_t)nu * 128 + c4 * 4] = acc;
                }
            }
        }
    }
}

// ---------------- layer-2 projection (weights-in-registers) ----------------
// [50000x32]@[32x256]. One wave per 8 nodes. Lane l owns cols 4l..4l+3 of
// [fs|fd]; W[:,4l..4l+3] in 32 float4 registers.
__global__ __launch_bounds__(256, 1) void k_proj(
    const float* __restrict__ x, const float* __restrict__ Wsrc,
    const float* __restrict__ bsrc, const float* __restrict__ Wdst,
    const float* __restrict__ bdst, unsigned short* __restrict__ fsh,
    float* __restrict__ fd) {
    int lane = threadIdx.x & 63;
    int wave = (blockIdx.x * 256 + threadIdx.x) >> 6;
    int cl = lane & 31;
    const float4* Wb = (lane < 32) ? (const float4*)Wsrc : (const float4*)Wdst;
    const float4* bb = (lane < 32) ? (const float4*)bsrc : (const float4*)bdst;
    float4 w[32];
#pragma unroll
    for (int k = 0; k < 32; k++) w[k] = Wb[k * 32 + cl];
    float4 bias = bb[cl];
    int n0 = wave * 8;
#pragma unroll 2
    for (int i = 0; i < 8; i++) {
        int n = n0 + i;
        if (n >= N_NODES) break;
        int nu = __builtin_amdgcn_readfirstlane(n);
        const float4* xr = (const float4*)(x + (size_t)nu * DIM_H);
        float4 acc = bias;
#pragma unroll
        for (int k4 = 0; k4 < 8; k4++) {
            float4 xv = xr[k4];
#pragma unroll
            for (int j = 0; j < 4; j++) {
                float xk = (j == 0) ? xv.x : (j == 1) ? xv.y : (j == 2) ? xv.z : xv.w;
                float4 wk = w[k4 * 4 + j];
                acc.x += xk * wk.x;
                acc.y += xk * wk.y;
                acc.z += xk * wk.z;
                acc.w += xk * wk.w;
            }
        }
        if (lane < 32) {
            ushort4 o;
            o.x = f2bf(acc.x);
            o.y = f2bf(acc.y);
            o.z = f2bf(acc.z);
            o.w = f2bf(acc.w);
            *(ushort4*)&fsh[(size_t)nu * 128 + cl * 4] = o;
        } else {
            *(float4*)&fd[(size_t)nu * 128 + cl * 4] = acc;
        }
    }
}

// ---------------- GAT gather (2 edges per wave-instruction) ----------------
__device__ __forceinline__ void pair_acc(const unsigned short* fsh, unsigned byteoff,
                                         float4 fdv, float4 a4, float4& acc,
                                         float& den, bool valid) {
    ushort4 u = *(const ushort4*)((const char*)fsh + byteoff);
    float f0 = bf2f(u.x), f1 = bf2f(u.y), f2 = bf2f(u.z), f3 = bf2f(u.w);
    float t0 = f0 + fdv.x; t0 = fmaxf(t0, NEG * t0);  // leaky (slope<1)
    float t1 = f1 + fdv.y; t1 = fmaxf(t1, NEG * t1);
    float t2 = f2 + fdv.z; t2 = fmaxf(t2, NEG * t2);
    float t3 = f3 + fdv.w; t3 = fmaxf(t3, NEG * t3);
    float p = t0 * a4.x + t1 * a4.y + t2 * a4.z + t3 * a4.w;
    p += __shfl_xor(p, 1, 64);
    p += __shfl_xor(p, 2, 64);
    p += __shfl_xor(p, 4, 64);
    float w = __expf(p);
    if (!valid) w = 0.f;
    den += w;
    acc.x += w * f0;
    acc.y += w * f1;
    acc.z += w * f2;
    acc.w += w * f3;
}

__global__ void k_gather(const unsigned short* __restrict__ fsh,
                         const float* __restrict__ fd, const float* __restrict__ attn,
                         const int* __restrict__ row, const int* __restrict__ adj,
                         float* __restrict__ xout, int do_relu) {
    int wave = threadIdx.x >> 6;
    int lane = threadIdx.x & 63;
    int n = blockIdx.x * 4 + wave;
    if (n >= N_NODES) return;
    int sub = lane & 31, e2 = lane >> 5;
    unsigned suboff = (unsigned)sub << 3;  // byte offset within a 256B row
    float4 a4 = ((const float4*)attn)[sub];
    float4 fdv = ((const float4*)(fd + (size_t)n * 128))[sub];
    float4 acc = {0.f, 0.f, 0.f, 0.f};
    float den = 0.f;
    int beg = row[n], end = row[n + 1];
    for (int base = beg; base < end; base += 64) {
        int m = end - base;
        if (m > 64) m = 64;
        int myadj = (lane < m) ? adj[base + lane] : 0;
        int j = 0;
        for (; j + 8 <= m; j += 8) {  // 4 pairs = 8 edges
            unsigned o0 = ((unsigned)__shfl(myadj, j + 0 + e2, 64) << 8) + suboff;
            unsigned o1 = ((unsigned)__shfl(myadj, j + 2 + e2, 64) << 8) + suboff;
            unsigned o2 = ((unsigned)__shfl(myadj, j + 4 + e2, 64) << 8) + suboff;
            unsigned o3 = ((unsigned)__shfl(myadj, j + 6 + e2, 64) << 8) + suboff;
            pair_acc(fsh, o0, fdv, a4, acc, den, true);
            pair_acc(fsh, o1, fdv, a4, acc, den, true);
            pair_acc(fsh, o2, fdv, a4, acc, den, true);
            pair_acc(fsh, o3, fdv, a4, acc, den, true);
        }
        for (; j < m; j += 2) {  // tail pairs (possibly half-valid)
            int idx = j + e2;
            bool valid = idx < m;
            unsigned o = ((unsigned)__shfl(myadj, valid ? idx : j, 64) << 8) + suboff;
            pair_acc(fsh, o, fdv, a4, acc, den, valid);
        }
    }
    den += __shfl_xor(den, 32, 64);
    acc.x += __shfl_xor(acc.x, 32, 64);
    acc.y += __shfl_xor(acc.y, 32, 64);
    acc.z += __shfl_xor(acc.z, 32, 64);
    acc.w += __shfl_xor(acc.w, 32, 64);
    float inv = den > 0.f ? 0.25f / den : 0.f;  // fold head-mean
    float4 o;
    o.x = acc.x * inv;
    o.y = acc.y * inv;
    o.z = acc.z * inv;
    o.w = acc.w * inv;
    o.x += __shfl_xor(o.x, 8, 64);
    o.y += __shfl_xor(o.y, 8, 64);
    o.z += __shfl_xor(o.z, 8, 64);
    o.w += __shfl_xor(o.w, 8, 64);
    o.x += __shfl_xor(o.x, 16, 64);
    o.y += __shfl_xor(o.y, 16, 64);
    o.z += __shfl_xor(o.z, 16, 64);
    o.w += __shfl_xor(o.w, 16, 64);
    if (do_relu) {
        o.x = o.x > 0.f ? o.x : 0.f;
        o.y = o.y > 0.f ? o.y : 0.f;
        o.z = o.z > 0.f ? o.z : 0.f;
        o.w = o.w > 0.f ? o.w : 0.f;
    }
    if (lane < 8) ((float4*)(xout + (size_t)n * 32))[lane] = o;
}

// sum x[n][32] over nodes -> partial[block][32]
__global__ void k_reduce(const float* __restrict__ x, float* __restrict__ partial) {
    int d = threadIdx.x & 31, g = threadIdx.x >> 5;
    float acc = 0.f;
    int stride = gridDim.x * 8;
    for (int n = blockIdx.x * 8 + g; n < N_NODES; n += stride) {
        acc += x[(size_t)n * 32 + d];
    }
    __shared__ float s[256];
    s[threadIdx.x] = acc;
    __syncthreads();
    for (int off = 128; off >= 32; off >>= 1) {
        if (threadIdx.x < off) s[threadIdx.x] += s[threadIdx.x + off];
        __syncthreads();
    }
    if (threadIdx.x < 32) partial[blockIdx.x * 32 + threadIdx.x] = s[threadIdx.x];
}

__global__ void k_final(const float* __restrict__ partial, const float* __restrict__ Wh1,
                        const float* __restrict__ bh1, const float* __restrict__ Wh2,
                        const float* __restrict__ bh2, float* __restrict__ out) {
    __shared__ float gv[32], gh[32], lg[16];
    int t = threadIdx.x;
    if (t < 32) {
        float s = 0.f;
        for (int b = 0; b < 256; b++) s += partial[b * 32 + t];
        gv[t] = s * (1.f / (float)N_NODES);
    }
    __syncthreads();
    if (t < 32) {
        float s = bh1[t];
        for (int d = 0; d < 32; d++) s += gv[d] * Wh1[d * 32 + t];
        gh[t] = s > 0.f ? s : 0.f;
    }
    __syncthreads();
    if (t < NCLS) {
        float s = bh2[t];
        for (int j = 0; j < 32; j++) s += gh[j] * Wh2[j * NCLS + t];
        lg[t] = s;
    }
    __syncthreads();
    if (t == 0) {
        float m = lg[0];
        for (int c = 1; c < NCLS; c++) m = fmaxf(m, lg[c]);
        float ex[NCLS], sum = 0.f;
        for (int c = 0; c < NCLS; c++) {
            ex[c] = __expf(lg[c] - m);
            sum += ex[c];
        }
        float inv = 1.f / sum;
        for (int c = 0; c < NCLS; c++) out[c] = ex[c] * inv;
    }
}

extern "C" void kernel_launch(void* const* d_in, const int* in_sizes, int n_in,
                              void* d_out, int out_size, void* d_ws, size_t ws_size,
                              hipStream_t stream) {
    const float* g_feats = (const float*)d_in[0];
    const int* edge_src = (const int*)d_in[1];
    const int* edge_dst = (const int*)d_in[2];
    const float* W_in = (const float*)d_in[3];
    const float* b_in = (const float*)d_in[4];
    const float* W1_src = (const float*)d_in[5];
    const float* b1_src = (const float*)d_in[6];
    const float* W1_dst = (const float*)d_in[7];
    const float* b1_dst = (const float*)d_in[8];
    const float* attn1 = (const float*)d_in[9];
    const float* W2_src = (const float*)d_in[10];
    const float* b2_src = (const float*)d_in[11];
    const float* W2_dst = (const float*)d_in[12];
    const float* b2_dst = (const float*)d_in[13];
    const float* attn2 = (const float*)d_in[14];
    const float* Wh1 = (const float*)d_in[15];
    const float* bh1 = (const float*)d_in[16];
    const float* Wh2 = (const float*)d_in[17];
    const float* bh2 = (const float*)d_in[18];

    // workspace layout
    float* x = (float*)d_ws;                                            // N*32 f32
    unsigned short* fsh = (unsigned short*)(x + (size_t)N_NODES * 32);  // N*128 bf16
    float* fd = (float*)(fsh + (size_t)N_NODES * 128);                  // N*128 f32
    float* partial = fd + (size_t)N_NODES * 128;                        // 256*32
    float* Wc = partial + 256 * 32;                                     // 64*256
    float* bc = Wc + 64 * 256;                                          // 256
    int* row = (int*)(bc + 256);                                        // N+1
    int* bh = row + N_NODES + 1;                                        // NBUCK
    int* bbase = bh + NBUCK;                                            // NBUCK+1
    int* gcur = bbase + NBUCK + 1;                                      // NBUCK
    unsigned* stage = (unsigned*)(gcur + NBUCK);                        // E
    int* adj = (int*)(stage + N_EDGES);                                 // E

    const int PB = (N_NODES + 31) / 32;  // proj grids: 4 waves x 8 nodes/block

    // CSR build (binned)
    hipMemsetAsync(bh, 0, NBUCK * sizeof(int), stream);
    k_bhist<<<(N_EDGES + 1023) / 1024, 256, 0, stream>>>(edge_dst, bh);
    k_bscan<<<1, 256, 0, stream>>>(bh, bbase, gcur);
    k_bin<<<(N_EDGES + 4095) / 4096, 256, 0, stream>>>(edge_src, edge_dst, gcur, stage);
    k_csr<<<NBUCK, 256, 0, stream>>>(stage, bbase, row, adj);

    // combined layer-1 weights (embed folded in)
    k_wcomb<<<64, 256, 0, stream>>>(W_in, b_in, W1_src, b1_src, W1_dst, b1_dst, Wc, bc);

    // layer 1 (fused embed+proj from g_feats)
    k_proj1<<<PB, 256, 0, stream>>>(g_feats, Wc, bc, fsh, fd);
    k_gather<<<(N_NODES + 3) / 4, 256, 0, stream>>>(fsh, fd, attn1, row, adj, x, 1);

    // layer 2
    k_proj<<<PB, 256, 0, stream>>>(x, W2_src, b2_src, W2_dst, b2_dst, fsh, fd);
    k_gather<<<(N_NODES + 3) / 4, 256, 0, stream>>>(fsh, fd, attn2, row, adj, x, 0);

    k_reduce<<<256, 256, 0, stream>>>(x, partial);
    k_final<<<1, 256, 0, stream>>>(partial, Wh1, bh1, Wh2, bh2, (float*)d_out);
}

// Round 9
// 226.100 us; speedup vs baseline: 1.0743x; 1.0743x over previous
//
#include <hip/hip_runtime.h>
#include <hip/hip_bf16.h>

#define N_NODES 50000
#define N_EDGES 800000
#define DIM_IN 64
#define DIM_H 32
#define HEADS 4
#define NCLS 10
#define NEG 0.2f
#define NBUCK 196  // ceil(50000/256) buckets of 256 dst nodes

// ---------------- CSR build (binned, single-writer adj regions) ----------------

__global__ void k_bhist(const int* __restrict__ dst, int* __restrict__ bh) {
    __shared__ int lh[NBUCK];
    for (int i = threadIdx.x; i < NBUCK; i += 256) lh[i] = 0;
    __syncthreads();
    int base = blockIdx.x * 1024 + threadIdx.x;
#pragma unroll
    for (int r = 0; r < 4; r++) {
        int e = base + r * 256;
        if (e < N_EDGES) atomicAdd(&lh[dst[e] >> 8], 1);
    }
    __syncthreads();
    for (int i = threadIdx.x; i < NBUCK; i += 256) {
        int c = lh[i];
        if (c) atomicAdd(&bh[i], c);
    }
}

__global__ void k_bscan(const int* __restrict__ bh, int* __restrict__ bbase,
                        int* __restrict__ gcur) {
    __shared__ int s[256];
    int t = threadIdx.x;
    int v = (t < NBUCK) ? bh[t] : 0;
    s[t] = v;
    __syncthreads();
    for (int off = 1; off < 256; off <<= 1) {
        int u = (t >= off) ? s[t - off] : 0;
        __syncthreads();
        s[t] += u;
        __syncthreads();
    }
    int excl = s[t] - v;
    if (t < NBUCK) {
        bbase[t] = excl;
        gcur[t] = excl;
    }
    if (t == 0) bbase[NBUCK] = N_EDGES;
}

__global__ void k_bin(const int* __restrict__ src, const int* __restrict__ dst,
                      int* __restrict__ gcur, unsigned* __restrict__ stage) {
    __shared__ int lh[NBUCK], chunk[NBUCK];
    int t = threadIdx.x;
    for (int i = t; i < NBUCK; i += 256) lh[i] = 0;
    __syncthreads();
    int e0 = blockIdx.x * 4096;
    unsigned pk[16];
    int bk[16];
#pragma unroll
    for (int r = 0; r < 16; r++) {
        int e = e0 + r * 256 + t;
        bool ok = e < N_EDGES;
        int s = ok ? src[e] : 0;
        int d = ok ? dst[e] : 0;
        bk[r] = ok ? (d >> 8) : -1;
        pk[r] = (unsigned)s | ((unsigned)(d & 255) << 16);
        if (ok) atomicAdd(&lh[bk[r]], 1);
    }
    __syncthreads();
    for (int i = t; i < NBUCK; i += 256) {
        int c = lh[i];
        chunk[i] = c ? atomicAdd(&gcur[i], c) : 0;
        lh[i] = 0;  // reuse as local cursor
    }
    __syncthreads();
#pragma unroll
    for (int r = 0; r < 16; r++) {
        if (bk[r] >= 0) {
            int lp = atomicAdd(&lh[bk[r]], 1);
            stage[chunk[bk[r]] + lp] = pk[r];
        }
    }
}

__global__ void k_csr(const unsigned* __restrict__ stage, const int* __restrict__ bbase,
                      int* __restrict__ row, int* __restrict__ adj) {
    __shared__ int lcnt[256], lcur[256], sc[256];
    int b = blockIdx.x, t = threadIdx.x;
    int s0 = bbase[b], s1 = bbase[b + 1];
    lcnt[t] = 0;
    __syncthreads();
    for (int i = s0 + t; i < s1; i += 256) atomicAdd(&lcnt[stage[i] >> 16], 1);
    __syncthreads();
    int v = lcnt[t];
    sc[t] = v;
    __syncthreads();
    for (int off = 1; off < 256; off <<= 1) {
        int u = (t >= off) ? sc[t - off] : 0;
        __syncthreads();
        sc[t] += u;
        __syncthreads();
    }
    int excl = sc[t] - v;
    int n = b * 256 + t;
    if (n < N_NODES) row[n] = s0 + excl;
    if (b == NBUCK - 1 && t == 0) row[N_NODES] = N_EDGES;
    lcur[t] = s0 + excl;
    __syncthreads();
    for (int i = s0 + t; i < s1; i += 256) {
        unsigned p = stage[i];
        int pos = atomicAdd(&lcur[p >> 16], 1);
        adj[pos] = (int)(p & 0xFFFFu);  // src fits 16 bits (N=50000<65536)
    }
}

// ---------------- helpers ----------------

__device__ __forceinline__ unsigned short f2bf(float v) {  // RTN f32->bf16
    unsigned u = __builtin_bit_cast(unsigned, v);
    u += 0x7FFFu + ((u >> 16) & 1u);
    return (unsigned short)(u >> 16);
}
__device__ __forceinline__ float bf2f(unsigned short h) {
    return __builtin_bit_cast(float, (unsigned)h << 16);
}

// ---------------- layer-1: fused embed + projection ----------------
// Per node (low-rank path, 10240 MACs): x = gf_row @ W_in + b_in (K=64->32),
// then fs|fd = x @ [W1s|W1d] + [b1s|b1d] (K=32->256). One wave per 16 nodes.
// Embed: lane (c=l&31, h=l>>5) accumulates half-K, shfl_xor(32) combine.
// x-row broadcast via per-wave LDS double-buffer (1 ds_write + 8 uniform
// ds_read_b128). Proj: lane l owns cols 4l..4l+3 of [fs(128)|fd(128)];
// W[:,4l..4l+3] in 32 float4 registers.
__global__ __launch_bounds__(256, 1) void k_fused1(
    const float* __restrict__ gf, const float* __restrict__ W_in,
    const float* __restrict__ b_in, const float* __restrict__ W1s,
    const float* __restrict__ b1s, const float* __restrict__ W1d,
    const float* __restrict__ b1d, unsigned short* __restrict__ fsh,
    float* __restrict__ fd) {
    __shared__ float4 xb[4][2][8];  // [wave][dbuf][32 floats]
    int lane = threadIdx.x & 63;
    int wvl = threadIdx.x >> 6;
    int wave = (blockIdx.x * 256 + threadIdx.x) >> 6;
    int c = lane & 31, h = lane >> 5;
    int n0 = wave * 16;
    if (n0 >= N_NODES) return;
    float wi[32];
#pragma unroll
    for (int k = 0; k < 32; k++) wi[k] = W_in[(h * 32 + k) * DIM_H + c];
    float bc = b_in[c];
    const float4* Wb = (lane < 32) ? (const float4*)W1s : (const float4*)W1d;
    const float4* bb = (lane < 32) ? (const float4*)b1s : (const float4*)b1d;
    float4 w[32];
#pragma unroll
    for (int k = 0; k < 32; k++) w[k] = Wb[k * 32 + c];
    float4 bias = bb[c];
#pragma unroll 2
    for (int i = 0; i < 16; i++) {  // 50000 % 16 == 0: all nodes valid
        int nu = __builtin_amdgcn_readfirstlane(n0 + i);
        const float4* gr = (const float4*)(gf + (size_t)nu * DIM_IN + h * 32);
        float a1 = 0.f;
#pragma unroll
        for (int k4 = 0; k4 < 8; k4++) {
            float4 xv = gr[k4];
            a1 += xv.x * wi[k4 * 4 + 0];
            a1 += xv.y * wi[k4 * 4 + 1];
            a1 += xv.z * wi[k4 * 4 + 2];
            a1 += xv.w * wi[k4 * 4 + 3];
        }
        a1 += __shfl_xor(a1, 32, 64);
        if (lane < 32) ((float*)&xb[wvl][i & 1][0])[c] = a1 + bc;
        float4 acc = bias;
#pragma unroll
        for (int k4 = 0; k4 < 8; k4++) {
            float4 xv = xb[wvl][i & 1][k4];
#pragma unroll
            for (int j = 0; j < 4; j++) {
                float xk = (j == 0) ? xv.x : (j == 1) ? xv.y : (j == 2) ? xv.z : xv.w;
                float4 wk = w[k4 * 4 + j];
                acc.x += xk * wk.x;
                acc.y += xk * wk.y;
                acc.z += xk * wk.z;
                acc.w += xk * wk.w;
            }
        }
        if (lane < 32) {
            ushort4 o;
            o.x = f2bf(acc.x);
            o.y = f2bf(acc.y);
            o.z = f2bf(acc.z);
            o.w = f2bf(acc.w);
            *(ushort4*)&fsh[(size_t)nu * 128 + c * 4] = o;
        } else {
            *(float4*)&fd[(size_t)nu * 128 + c * 4] = acc;
        }
    }
}

// ---------------- layer-2 projection (weights-in-registers) ----------------
// [50000x32]@[32x256]. One wave per 16 nodes. Lane l owns cols 4l..4l+3 of
// [fs|fd]; W[:,4l..4l+3] in 32 float4 registers.
__global__ __launch_bounds__(256, 1) void k_proj(
    const float* __restrict__ x, const float* __restrict__ Wsrc,
    const float* __restrict__ bsrc, const float* __restrict__ Wdst,
    const float* __restrict__ bdst, unsigned short* __restrict__ fsh,
    float* __restrict__ fd) {
    int lane = threadIdx.x & 63;
    int wave = (blockIdx.x * 256 + threadIdx.x) >> 6;
    int cl = lane & 31;
    int n0 = wave * 16;
    if (n0 >= N_NODES) return;
    const float4* Wb = (lane < 32) ? (const float4*)Wsrc : (const float4*)Wdst;
    const float4* bb = (lane < 32) ? (const float4*)bsrc : (const float4*)bdst;
    float4 w[32];
#pragma unroll
    for (int k = 0; k < 32; k++) w[k] = Wb[k * 32 + cl];
    float4 bias = bb[cl];
#pragma unroll 2
    for (int i = 0; i < 16; i++) {
        int nu = __builtin_amdgcn_readfirstlane(n0 + i);
        const float4* xr = (const float4*)(x + (size_t)nu * DIM_H);
        float4 acc = bias;
#pragma unroll
        for (int k4 = 0; k4 < 8; k4++) {
            float4 xv = xr[k4];
#pragma unroll
            for (int j = 0; j < 4; j++) {
                float xk = (j == 0) ? xv.x : (j == 1) ? xv.y : (j == 2) ? xv.z : xv.w;
                float4 wk = w[k4 * 4 + j];
                acc.x += xk * wk.x;
                acc.y += xk * wk.y;
                acc.z += xk * wk.z;
                acc.w += xk * wk.w;
            }
        }
        if (lane < 32) {
            ushort4 o;
            o.x = f2bf(acc.x);
            o.y = f2bf(acc.y);
            o.z = f2bf(acc.z);
            o.w = f2bf(acc.w);
            *(ushort4*)&fsh[(size_t)nu * 128 + cl * 4] = o;
        } else {
            *(float4*)&fd[(size_t)nu * 128 + cl * 4] = acc;
        }
    }
}

// ---------------- GAT gather (2 edges per wave-instruction) ----------------
__device__ __forceinline__ void pair_acc(const unsigned short* fsh, unsigned byteoff,
                                         float4 fdv, float4 a4, float4& acc,
                                         float& den, bool valid) {
    ushort4 u = *(const ushort4*)((const char*)fsh + byteoff);
    float f0 = bf2f(u.x), f1 = bf2f(u.y), f2 = bf2f(u.z), f3 = bf2f(u.w);
    float t0 = f0 + fdv.x; t0 = fmaxf(t0, NEG * t0);  // leaky (slope<1)
    float t1 = f1 + fdv.y; t1 = fmaxf(t1, NEG * t1);
    float t2 = f2 + fdv.z; t2 = fmaxf(t2, NEG * t2);
    float t3 = f3 + fdv.w; t3 = fmaxf(t3, NEG * t3);
    float p = t0 * a4.x + t1 * a4.y + t2 * a4.z + t3 * a4.w;
    p += __shfl_xor(p, 1, 64);
    p += __shfl_xor(p, 2, 64);
    p += __shfl_xor(p, 4, 64);
    float w = __expf(p);
    if (!valid) w = 0.f;
    den += w;
    acc.x += w * f0;
    acc.y += w * f1;
    acc.z += w * f2;
    acc.w += w * f3;
}

__global__ void k_gather(const unsigned short* __restrict__ fsh,
                         const float* __restrict__ fd, const float* __restrict__ attn,
                         const int* __restrict__ row, const int* __restrict__ adj,
                         float* __restrict__ xout, int do_relu) {
    int wave = threadIdx.x >> 6;
    int lane = threadIdx.x & 63;
    int n = blockIdx.x * 4 + wave;
    if (n >= N_NODES) return;
    int sub = lane & 31, e2 = lane >> 5;
    unsigned suboff = (unsigned)sub << 3;  // byte offset within a 256B row
    float4 a4 = ((const float4*)attn)[sub];
    float4 fdv = ((const float4*)(fd + (size_t)n * 128))[sub];
    float4 acc = {0.f, 0.f, 0.f, 0.f};
    float den = 0.f;
    int beg = row[n], end = row[n + 1];
    for (int base = beg; base < end; base += 64) {
        int m = end - base;
        if (m > 64) m = 64;
        int myadj = (lane < m) ? adj[base + lane] : 0;
        int j = 0;
        for (; j + 8 <= m; j += 8) {  // 4 pairs = 8 edges
            unsigned o0 = ((unsigned)__shfl(myadj, j + 0 + e2, 64) << 8) + suboff;
            unsigned o1 = ((unsigned)__shfl(myadj, j + 2 + e2, 64) << 8) + suboff;
            unsigned o2 = ((unsigned)__shfl(myadj, j + 4 + e2, 64) << 8) + suboff;
            unsigned o3 = ((unsigned)__shfl(myadj, j + 6 + e2, 64) << 8) + suboff;
            pair_acc(fsh, o0, fdv, a4, acc, den, true);
            pair_acc(fsh, o1, fdv, a4, acc, den, true);
            pair_acc(fsh, o2, fdv, a4, acc, den, true);
            pair_acc(fsh, o3, fdv, a4, acc, den, true);
        }
        for (; j < m; j += 2) {  // tail pairs (possibly half-valid)
            int idx = j + e2;
            bool valid = idx < m;
            unsigned o = ((unsigned)__shfl(myadj, valid ? idx : j, 64) << 8) + suboff;
            pair_acc(fsh, o, fdv, a4, acc, den, valid);
        }
    }
    den += __shfl_xor(den, 32, 64);
    acc.x += __shfl_xor(acc.x, 32, 64);
    acc.y += __shfl_xor(acc.y, 32, 64);
    acc.z += __shfl_xor(acc.z, 32, 64);
    acc.w += __shfl_xor(acc.w, 32, 64);
    float inv = den > 0.f ? 0.25f / den : 0.f;  // fold head-mean
    float4 o;
    o.x = acc.x * inv;
    o.y = acc.y * inv;
    o.z = acc.z * inv;
    o.w = acc.w * inv;
    o.x += __shfl_xor(o.x, 8, 64);
    o.y += __shfl_xor(o.y, 8, 64);
    o.z += __shfl_xor(o.z, 8, 64);
    o.w += __shfl_xor(o.w, 8, 64);
    o.x += __shfl_xor(o.x, 16, 64);
    o.y += __shfl_xor(o.y, 16, 64);
    o.z += __shfl_xor(o.z, 16, 64);
    o.w += __shfl_xor(o.w, 16, 64);
    if (do_relu) {
        o.x = o.x > 0.f ? o.x : 0.f;
        o.y = o.y > 0.f ? o.y : 0.f;
        o.z = o.z > 0.f ? o.z : 0.f;
        o.w = o.w > 0.f ? o.w : 0.f;
    }
    if (lane < 8) ((float4*)(xout + (size_t)n * 32))[lane] = o;
}

// sum x[n][32] over nodes -> partial[block][32]
__global__ void k_reduce(const float* __restrict__ x, float* __restrict__ partial) {
    int d = threadIdx.x & 31, g = threadIdx.x >> 5;
    float acc = 0.f;
    int stride = gridDim.x * 8;
    for (int n = blockIdx.x * 8 + g; n < N_NODES; n += stride) {
        acc += x[(size_t)n * 32 + d];
    }
    __shared__ float s[256];
    s[threadIdx.x] = acc;
    __syncthreads();
    for (int off = 128; off >= 32; off >>= 1) {
        if (threadIdx.x < off) s[threadIdx.x] += s[threadIdx.x + off];
        __syncthreads();
    }
    if (threadIdx.x < 32) partial[blockIdx.x * 32 + threadIdx.x] = s[threadIdx.x];
}

__global__ void k_final(const float* __restrict__ partial, const float* __restrict__ Wh1,
                        const float* __restrict__ bh1, const float* __restrict__ Wh2,
                        const float* __restrict__ bh2, float* __restrict__ out) {
    __shared__ float gv[32], gh[32], lg[16];
    int t = threadIdx.x;
    if (t < 32) {
        float s = 0.f;
        for (int b = 0; b < 256; b++) s += partial[b * 32 + t];
        gv[t] = s * (1.f / (float)N_NODES);
    }
    __syncthreads();
    if (t < 32) {
        float s = bh1[t];
        for (int d = 0; d < 32; d++) s += gv[d] * Wh1[d * 32 + t];
        gh[t] = s > 0.f ? s : 0.f;
    }
    __syncthreads();
    if (t < NCLS) {
        float s = bh2[t];
        for (int j = 0; j < 32; j++) s += gh[j] * Wh2[j * NCLS + t];
        lg[t] = s;
    }
    __syncthreads();
    if (t == 0) {
        float m = lg[0];
        for (int c = 1; c < NCLS; c++) m = fmaxf(m, lg[c]);
        float ex[NCLS], sum = 0.f;
        for (int c = 0; c < NCLS; c++) {
            ex[c] = __expf(lg[c] - m);
            sum += ex[c];
        }
        float inv = 1.f / sum;
        for (int c = 0; c < NCLS; c++) out[c] = ex[c] * inv;
    }
}

extern "C" void kernel_launch(void* const* d_in, const int* in_sizes, int n_in,
                              void* d_out, int out_size, void* d_ws, size_t ws_size,
                              hipStream_t stream) {
    const float* g_feats = (const float*)d_in[0];
    const int* edge_src = (const int*)d_in[1];
    const int* edge_dst = (const int*)d_in[2];
    const float* W_in = (const float*)d_in[3];
    const float* b_in = (const float*)d_in[4];
    const float* W1_src = (const float*)d_in[5];
    const float* b1_src = (const float*)d_in[6];
    const float* W1_dst = (const float*)d_in[7];
    const float* b1_dst = (const float*)d_in[8];
    const float* attn1 = (const float*)d_in[9];
    const float* W2_src = (const float*)d_in[10];
    const float* b2_src = (const float*)d_in[11];
    const float* W2_dst = (const float*)d_in[12];
    const float* b2_dst = (const float*)d_in[13];
    const float* attn2 = (const float*)d_in[14];
    const float* Wh1 = (const float*)d_in[15];
    const float* bh1 = (const float*)d_in[16];
    const float* Wh2 = (const float*)d_in[17];
    const float* bh2 = (const float*)d_in[18];

    // workspace layout
    float* x = (float*)d_ws;                                            // N*32 f32
    unsigned short* fsh = (unsigned short*)(x + (size_t)N_NODES * 32);  // N*128 bf16
    float* fd = (float*)(fsh + (size_t)N_NODES * 128);                  // N*128 f32
    float* partial = fd + (size_t)N_NODES * 128;                        // 256*32
    int* row = (int*)(partial + 256 * 32);                              // N+1
    int* bh = row + N_NODES + 1;                                        // NBUCK
    int* bbase = bh + NBUCK;                                            // NBUCK+1
    int* gcur = bbase + NBUCK + 1;                                      // NBUCK
    unsigned* stage = (unsigned*)(gcur + NBUCK);                        // E
    int* adj = (int*)(stage + N_EDGES);                                 // E

    const int WB = (N_NODES + 63) / 64;  // 782: 4 waves x 16 nodes per block

    // CSR build (binned)
    hipMemsetAsync(bh, 0, NBUCK * sizeof(int), stream);
    k_bhist<<<(N_EDGES + 1023) / 1024, 256, 0, stream>>>(edge_dst, bh);
    k_bscan<<<1, 256, 0, stream>>>(bh, bbase, gcur);
    k_bin<<<(N_EDGES + 4095) / 4096, 256, 0, stream>>>(edge_src, edge_dst, gcur, stage);
    k_csr<<<NBUCK, 256, 0, stream>>>(stage, bbase, row, adj);

    // layer 1 (pipeline-fused embed+proj, low-rank path)
    k_fused1<<<WB, 256, 0, stream>>>(g_feats, W_in, b_in, W1_src, b1_src, W1_dst,
                                     b1_dst, fsh, fd);
    k_gather<<<(N_NODES + 3) / 4, 256, 0, stream>>>(fsh, fd, attn1, row, adj, x, 1);

    // layer 2
    k_proj<<<WB, 256, 0, stream>>>(x, W2_src, b2_src, W2_dst, b2_dst, fsh, fd);
    k_gather<<<(N_NODES + 3) / 4, 256, 0, stream>>>(fsh, fd, attn2, row, adj, x, 0);

    k_reduce<<<256, 256, 0, stream>>>(x, partial);
    k_final<<<1, 256, 0, stream>>>(partial, Wh1, bh1, Wh2, bh2, (float*)d_out);
}

// Round 10
// 198.165 us; speedup vs baseline: 1.2258x; 1.1410x over previous
//
#include <hip/hip_runtime.h>
#include <hip/hip_bf16.h>

#define N_NODES 50000
#define N_EDGES 800000
#define DIM_IN 64
#define DIM_H 32
#define HEADS 4
#define NCLS 10
#define NEG 0.2f
#define NBUCK 196  // ceil(50000/256) buckets of 256 dst nodes
#define NPW 25     // nodes per wave in proj kernels (50000 = 2000 waves * 25)

// ---------------- CSR build (binned, single-writer adj regions) ----------------

__global__ void k_bhist(const int* __restrict__ dst, int* __restrict__ bh) {
    __shared__ int lh[NBUCK];
    for (int i = threadIdx.x; i < NBUCK; i += 256) lh[i] = 0;
    __syncthreads();
    int base = blockIdx.x * 1024 + threadIdx.x;
#pragma unroll
    for (int r = 0; r < 4; r++) {
        int e = base + r * 256;
        if (e < N_EDGES) atomicAdd(&lh[dst[e] >> 8], 1);
    }
    __syncthreads();
    for (int i = threadIdx.x; i < NBUCK; i += 256) {
        int c = lh[i];
        if (c) atomicAdd(&bh[i], c);
    }
}

__global__ void k_bscan(const int* __restrict__ bh, int* __restrict__ bbase,
                        int* __restrict__ gcur) {
    __shared__ int s[256];
    int t = threadIdx.x;
    int v = (t < NBUCK) ? bh[t] : 0;
    s[t] = v;
    __syncthreads();
    for (int off = 1; off < 256; off <<= 1) {
        int u = (t >= off) ? s[t - off] : 0;
        __syncthreads();
        s[t] += u;
        __syncthreads();
    }
    int excl = s[t] - v;
    if (t < NBUCK) {
        bbase[t] = excl;
        gcur[t] = excl;
    }
    if (t == 0) bbase[NBUCK] = N_EDGES;
}

__global__ void k_bin(const int* __restrict__ src, const int* __restrict__ dst,
                      int* __restrict__ gcur, unsigned* __restrict__ stage) {
    __shared__ int lh[NBUCK], chunk[NBUCK];
    int t = threadIdx.x;
    for (int i = t; i < NBUCK; i += 256) lh[i] = 0;
    __syncthreads();
    int e0 = blockIdx.x * 4096;
    unsigned pk[16];
    int bk[16];
#pragma unroll
    for (int r = 0; r < 16; r++) {
        int e = e0 + r * 256 + t;
        bool ok = e < N_EDGES;
        int s = ok ? src[e] : 0;
        int d = ok ? dst[e] : 0;
        bk[r] = ok ? (d >> 8) : -1;
        pk[r] = (unsigned)s | ((unsigned)(d & 255) << 16);
        if (ok) atomicAdd(&lh[bk[r]], 1);
    }
    __syncthreads();
    for (int i = t; i < NBUCK; i += 256) {
        int c = lh[i];
        chunk[i] = c ? atomicAdd(&gcur[i], c) : 0;
        lh[i] = 0;  // reuse as local cursor
    }
    __syncthreads();
#pragma unroll
    for (int r = 0; r < 16; r++) {
        if (bk[r] >= 0) {
            int lp = atomicAdd(&lh[bk[r]], 1);
            stage[chunk[bk[r]] + lp] = pk[r];
        }
    }
}

__global__ void k_csr(const unsigned* __restrict__ stage, const int* __restrict__ bbase,
                      int* __restrict__ row, int* __restrict__ adj) {
    __shared__ int lcnt[256], lcur[256], sc[256];
    int b = blockIdx.x, t = threadIdx.x;
    int s0 = bbase[b], s1 = bbase[b + 1];
    lcnt[t] = 0;
    __syncthreads();
    for (int i = s0 + t; i < s1; i += 256) atomicAdd(&lcnt[stage[i] >> 16], 1);
    __syncthreads();
    int v = lcnt[t];
    sc[t] = v;
    __syncthreads();
    for (int off = 1; off < 256; off <<= 1) {
        int u = (t >= off) ? sc[t - off] : 0;
        __syncthreads();
        sc[t] += u;
        __syncthreads();
    }
    int excl = sc[t] - v;
    int n = b * 256 + t;
    if (n < N_NODES) row[n] = s0 + excl;
    if (b == NBUCK - 1 && t == 0) row[N_NODES] = N_EDGES;
    lcur[t] = s0 + excl;
    __syncthreads();
    for (int i = s0 + t; i < s1; i += 256) {
        unsigned p = stage[i];
        int pos = atomicAdd(&lcur[p >> 16], 1);
        adj[pos] = (int)(p & 0xFFFFu);  // src fits 16 bits (N=50000<65536)
    }
}

// ---------------- helpers ----------------

__device__ __forceinline__ unsigned short f2bf(float v) {  // RTN f32->bf16
    unsigned u = __builtin_bit_cast(unsigned, v);
    u += 0x7FFFu + ((u >> 16) & 1u);
    return (unsigned short)(u >> 16);
}
__device__ __forceinline__ float bfLO(unsigned u) {
    return __builtin_bit_cast(float, u << 16);
}
__device__ __forceinline__ float bfHI(unsigned u) {
    return __builtin_bit_cast(float, u & 0xFFFF0000u);
}

// ---------------- layer-1: fused embed + projection ----------------
// Per node (low-rank, 10240 MACs): x = gf_row@W_in+b_in (64->32), then
// fs|fd = x@[W1s|W1d]+[b1s|b1d] (32->256). One wave per NPW nodes. Embed:
// lane (c=l&31,h=l>>5) half-K accumulate, shfl_xor(32) combine; x-row
// broadcast via per-wave LDS double-buffer. Proj: lane l owns cols 4l..4l+3
// of [fs(128)|fd(128)]; W[:,4l..4l+3] in 32 float4 registers.
__global__ __launch_bounds__(256, 2) void k_fused1(
    const float* __restrict__ gf, const float* __restrict__ W_in,
    const float* __restrict__ b_in, const float* __restrict__ W1s,
    const float* __restrict__ b1s, const float* __restrict__ W1d,
    const float* __restrict__ b1d, unsigned short* __restrict__ fsh,
    float* __restrict__ fd) {
    __shared__ float4 xb[4][2][8];  // [wave][dbuf][32 floats]
    int lane = threadIdx.x & 63;
    int wvl = threadIdx.x >> 6;
    int wave = (blockIdx.x * 256 + threadIdx.x) >> 6;
    int c = lane & 31, h = lane >> 5;
    int n0 = wave * NPW;
    if (n0 >= N_NODES) return;
    float wi[32];
#pragma unroll
    for (int k = 0; k < 32; k++) wi[k] = W_in[(h * 32 + k) * DIM_H + c];
    float bc = b_in[c];
    const float4* Wb = (lane < 32) ? (const float4*)W1s : (const float4*)W1d;
    const float4* bb = (lane < 32) ? (const float4*)b1s : (const float4*)b1d;
    float4 w[32];
#pragma unroll
    for (int k = 0; k < 32; k++) w[k] = Wb[k * 32 + c];
    float4 bias = bb[c];
#pragma unroll 2
    for (int i = 0; i < NPW; i++) {  // 50000 % 25 == 0: all nodes valid
        int nu = __builtin_amdgcn_readfirstlane(n0 + i);
        const float4* gr = (const float4*)(gf + (size_t)nu * DIM_IN + h * 32);
        float a1 = 0.f;
#pragma unroll
        for (int k4 = 0; k4 < 8; k4++) {
            float4 xv = gr[k4];
            a1 += xv.x * wi[k4 * 4 + 0];
            a1 += xv.y * wi[k4 * 4 + 1];
            a1 += xv.z * wi[k4 * 4 + 2];
            a1 += xv.w * wi[k4 * 4 + 3];
        }
        a1 += __shfl_xor(a1, 32, 64);
        if (lane < 32) ((float*)&xb[wvl][i & 1][0])[c] = a1 + bc;
        float4 acc = bias;
#pragma unroll
        for (int k4 = 0; k4 < 8; k4++) {
            float4 xv = xb[wvl][i & 1][k4];
#pragma unroll
            for (int j = 0; j < 4; j++) {
                float xk = (j == 0) ? xv.x : (j == 1) ? xv.y : (j == 2) ? xv.z : xv.w;
                float4 wk = w[k4 * 4 + j];
                acc.x += xk * wk.x;
                acc.y += xk * wk.y;
                acc.z += xk * wk.z;
                acc.w += xk * wk.w;
            }
        }
        if (lane < 32) {
            ushort4 o;
            o.x = f2bf(acc.x);
            o.y = f2bf(acc.y);
            o.z = f2bf(acc.z);
            o.w = f2bf(acc.w);
            *(ushort4*)&fsh[(size_t)nu * 128 + c * 4] = o;
        } else {
            *(float4*)&fd[(size_t)nu * 128 + c * 4] = acc;
        }
    }
}

// ---------------- layer-2 projection (weights-in-registers) ----------------
__global__ __launch_bounds__(256, 2) void k_proj(
    const float* __restrict__ x, const float* __restrict__ Wsrc,
    const float* __restrict__ bsrc, const float* __restrict__ Wdst,
    const float* __restrict__ bdst, unsigned short* __restrict__ fsh,
    float* __restrict__ fd) {
    int lane = threadIdx.x & 63;
    int wave = (blockIdx.x * 256 + threadIdx.x) >> 6;
    int cl = lane & 31;
    int n0 = wave * NPW;
    if (n0 >= N_NODES) return;
    const float4* Wb = (lane < 32) ? (const float4*)Wsrc : (const float4*)Wdst;
    const float4* bb = (lane < 32) ? (const float4*)bsrc : (const float4*)bdst;
    float4 w[32];
#pragma unroll
    for (int k = 0; k < 32; k++) w[k] = Wb[k * 32 + cl];
    float4 bias = bb[cl];
#pragma unroll 2
    for (int i = 0; i < NPW; i++) {
        int nu = __builtin_amdgcn_readfirstlane(n0 + i);
        const float4* xr = (const float4*)(x + (size_t)nu * DIM_H);
        float4 acc = bias;
#pragma unroll
        for (int k4 = 0; k4 < 8; k4++) {
            float4 xv = xr[k4];
#pragma unroll
            for (int j = 0; j < 4; j++) {
                float xk = (j == 0) ? xv.x : (j == 1) ? xv.y : (j == 2) ? xv.z : xv.w;
                float4 wk = w[k4 * 4 + j];
                acc.x += xk * wk.x;
                acc.y += xk * wk.y;
                acc.z += xk * wk.z;
                acc.w += xk * wk.w;
            }
        }
        if (lane < 32) {
            ushort4 o;
            o.x = f2bf(acc.x);
            o.y = f2bf(acc.y);
            o.z = f2bf(acc.z);
            o.w = f2bf(acc.w);
            *(ushort4*)&fsh[(size_t)nu * 128 + cl * 4] = o;
        } else {
            *(float4*)&fd[(size_t)nu * 128 + cl * 4] = acc;
        }
    }
}

// ---------------- GAT gather (4 edges per wave-instruction) ----------------
// One wave per destination node. Lane = (eps=lane>>4 edge slot, sub=lane&15).
// Lane owns 8 dims (sub*8..+7) of its edge's fs row: one dwordx4 (16B) load
// covers 4 edges per instruction. Head h=sub>>2 (4 lanes/head): score reduce
// = 2 quad-perm shfl_xor. Edge-slot combine xor16/32; head-mean xor4/8.
// Softmax shift dropped (shift-invariant; |logits| small).
__device__ __forceinline__ void edge4(uint4 u, const float* a8, const float* f8d,
                                      float* acc, float& den, bool valid) {
    float f[8];
    f[0] = bfLO(u.x); f[1] = bfHI(u.x);
    f[2] = bfLO(u.y); f[3] = bfHI(u.y);
    f[4] = bfLO(u.z); f[5] = bfHI(u.z);
    f[6] = bfLO(u.w); f[7] = bfHI(u.w);
    float p = 0.f;
#pragma unroll
    for (int j = 0; j < 8; j++) {
        float t = f[j] + f8d[j];
        t = fmaxf(t, NEG * t);  // leaky (slope<1)
        p += t * a8[j];
    }
    p += __shfl_xor(p, 1, 64);
    p += __shfl_xor(p, 2, 64);
    float w = __expf(p);
    if (!valid) w = 0.f;
    den += w;
#pragma unroll
    for (int j = 0; j < 8; j++) acc[j] += w * f[j];
}

__global__ void k_gather(const unsigned short* __restrict__ fsh,
                         const float* __restrict__ fd, const float* __restrict__ attn,
                         const int* __restrict__ row, const int* __restrict__ adj,
                         float* __restrict__ xout, float* __restrict__ gpart,
                         int mode) {  // mode 0: relu + store x; 1: graph-mean reduce
    __shared__ float bsum[32];
    int tid = threadIdx.x;
    if (mode) {
        if (tid < 32) bsum[tid] = 0.f;
        __syncthreads();
    }
    int wave = tid >> 6;
    int lane = tid & 63;
    int n = blockIdx.x * 4 + wave;  // 50000 = 12500 blocks * 4: always valid
    int sub = lane & 15, eps = lane >> 4;
    unsigned suboff = (unsigned)sub << 4;  // 16B per lane within 256B row
    float a8[8], f8d[8];
    {
        const float4* ap = (const float4*)attn + sub * 2;
        float4 t0 = ap[0], t1 = ap[1];
        a8[0] = t0.x; a8[1] = t0.y; a8[2] = t0.z; a8[3] = t0.w;
        a8[4] = t1.x; a8[5] = t1.y; a8[6] = t1.z; a8[7] = t1.w;
        const float4* fp = (const float4*)(fd + (size_t)n * 128) + sub * 2;
        float4 d0 = fp[0], d1 = fp[1];
        f8d[0] = d0.x; f8d[1] = d0.y; f8d[2] = d0.z; f8d[3] = d0.w;
        f8d[4] = d1.x; f8d[5] = d1.y; f8d[6] = d1.z; f8d[7] = d1.w;
    }
    float acc[8] = {0.f, 0.f, 0.f, 0.f, 0.f, 0.f, 0.f, 0.f};
    float den = 0.f;
    int beg = row[n], end = row[n + 1];
    for (int base = beg; base < end; base += 64) {
        int m = end - base;
        if (m > 64) m = 64;
        int myadj = (lane < m) ? adj[base + lane] : 0;
        int j = 0;
        for (; j + 8 <= m; j += 8) {  // 2 groups of 4 edges, both loads in flight
            unsigned oa = ((unsigned)__shfl(myadj, j + eps, 64) << 8) + suboff;
            unsigned ob = ((unsigned)__shfl(myadj, j + 4 + eps, 64) << 8) + suboff;
            uint4 ua = *(const uint4*)((const char*)fsh + oa);
            uint4 ub = *(const uint4*)((const char*)fsh + ob);
            edge4(ua, a8, f8d, acc, den, true);
            edge4(ub, a8, f8d, acc, den, true);
        }
        for (; j < m; j += 4) {  // tail group (possibly partial)
            int idx = j + eps;
            bool valid = idx < m;
            unsigned o = ((unsigned)__shfl(myadj, valid ? idx : j, 64) << 8) + suboff;
            uint4 u = *(const uint4*)((const char*)fsh + o);
            edge4(u, a8, f8d, acc, den, valid);
        }
    }
    // combine the 4 edge slots
    den += __shfl_xor(den, 16, 64);
    den += __shfl_xor(den, 32, 64);
#pragma unroll
    for (int j = 0; j < 8; j++) {
        acc[j] += __shfl_xor(acc[j], 16, 64);
        acc[j] += __shfl_xor(acc[j], 32, 64);
    }
    float inv = den > 0.f ? 1.f / den : 0.f;
    float o[8];
#pragma unroll
    for (int j = 0; j < 8; j++) {
        float v = acc[j] * inv;
        v += __shfl_xor(v, 4, 64);  // head mean: sum over h (lane bits 2,3)
        v += __shfl_xor(v, 8, 64);
        o[j] = v * 0.25f;
    }
    if (mode == 0) {
        if (lane < 4) {  // sub=lane holds dims lane*8..+7 (h=0 copy)
            float4 lo, hi;
            lo.x = fmaxf(o[0], 0.f); lo.y = fmaxf(o[1], 0.f);
            lo.z = fmaxf(o[2], 0.f); lo.w = fmaxf(o[3], 0.f);
            hi.x = fmaxf(o[4], 0.f); hi.y = fmaxf(o[5], 0.f);
            hi.z = fmaxf(o[6], 0.f); hi.w = fmaxf(o[7], 0.f);
            float4* xp = (float4*)(xout + (size_t)n * 32 + lane * 8);
            xp[0] = lo;
            xp[1] = hi;
        }
    } else {
        if (lane < 4) {
#pragma unroll
            for (int j = 0; j < 8; j++) atomicAdd(&bsum[lane * 8 + j], o[j]);
        }
        __syncthreads();
        if (tid < 32) atomicAdd(&gpart[(blockIdx.x & 63) * 32 + tid], bsum[tid]);
    }
}

__global__ void k_final(const float* __restrict__ gpart, const float* __restrict__ Wh1,
                        const float* __restrict__ bh1, const float* __restrict__ Wh2,
                        const float* __restrict__ bh2, float* __restrict__ out) {
    __shared__ float gv[32], gh[32], lg[16];
    int t = threadIdx.x;
    if (t < 32) {
        float s = 0.f;
        for (int b = 0; b < 64; b++) s += gpart[b * 32 + t];
        gv[t] = s * (1.f / (float)N_NODES);
    }
    __syncthreads();
    if (t < 32) {
        float s = bh1[t];
        for (int d = 0; d < 32; d++) s += gv[d] * Wh1[d * 32 + t];
        gh[t] = s > 0.f ? s : 0.f;
    }
    __syncthreads();
    if (t < NCLS) {
        float s = bh2[t];
        for (int j = 0; j < 32; j++) s += gh[j] * Wh2[j * NCLS + t];
        lg[t] = s;
    }
    __syncthreads();
    if (t == 0) {
        float m = lg[0];
        for (int c = 1; c < NCLS; c++) m = fmaxf(m, lg[c]);
        float ex[NCLS], sum = 0.f;
        for (int c = 0; c < NCLS; c++) {
            ex[c] = __expf(lg[c] - m);
            sum += ex[c];
        }
        float inv = 1.f / sum;
        for (int c = 0; c < NCLS; c++) out[c] = ex[c] * inv;
    }
}

extern "C" void kernel_launch(void* const* d_in, const int* in_sizes, int n_in,
                              void* d_out, int out_size, void* d_ws, size_t ws_size,
                              hipStream_t stream) {
    const float* g_feats = (const float*)d_in[0];
    const int* edge_src = (const int*)d_in[1];
    const int* edge_dst = (const int*)d_in[2];
    const float* W_in = (const float*)d_in[3];
    const float* b_in = (const float*)d_in[4];
    const float* W1_src = (const float*)d_in[5];
    const float* b1_src = (const float*)d_in[6];
    const float* W1_dst = (const float*)d_in[7];
    const float* b1_dst = (const float*)d_in[8];
    const float* attn1 = (const float*)d_in[9];
    const float* W2_src = (const float*)d_in[10];
    const float* b2_src = (const float*)d_in[11];
    const float* W2_dst = (const float*)d_in[12];
    const float* b2_dst = (const float*)d_in[13];
    const float* attn2 = (const float*)d_in[14];
    const float* Wh1 = (const float*)d_in[15];
    const float* bh1 = (const float*)d_in[16];
    const float* Wh2 = (const float*)d_in[17];
    const float* bh2 = (const float*)d_in[18];

    // workspace layout
    float* x = (float*)d_ws;                                            // N*32 f32
    unsigned short* fsh = (unsigned short*)(x + (size_t)N_NODES * 32);  // N*128 bf16
    float* fd = (float*)(fsh + (size_t)N_NODES * 128);                  // N*128 f32
    float* gpart = fd + (size_t)N_NODES * 128;                          // 64*32
    int* bh = (int*)(gpart + 64 * 32);                                  // NBUCK
    int* bbase = bh + NBUCK;                                            // NBUCK+1
    int* gcur = bbase + NBUCK + 1;                                      // NBUCK
    int* row = gcur + NBUCK;                                            // N+1
    unsigned* stage = (unsigned*)(row + N_NODES + 1);                   // E
    int* adj = (int*)(stage + N_EDGES);                                 // E

    const int WB = (N_NODES / NPW + 3) / 4;  // 500 blocks: 4 waves x 25 nodes

    // zero gpart + bucket histogram in one memset (adjacent)
    hipMemsetAsync(gpart, 0, (64 * 32 + NBUCK) * sizeof(int), stream);

    // CSR build (binned)
    k_bhist<<<(N_EDGES + 1023) / 1024, 256, 0, stream>>>(edge_dst, bh);
    k_bscan<<<1, 256, 0, stream>>>(bh, bbase, gcur);
    k_bin<<<(N_EDGES + 4095) / 4096, 256, 0, stream>>>(edge_src, edge_dst, gcur, stage);
    k_csr<<<NBUCK, 256, 0, stream>>>(stage, bbase, row, adj);

    // layer 1 (pipeline-fused embed+proj, low-rank path)
    k_fused1<<<WB, 256, 0, stream>>>(g_feats, W_in, b_in, W1_src, b1_src, W1_dst,
                                     b1_dst, fsh, fd);
    k_gather<<<N_NODES / 4, 256, 0, stream>>>(fsh, fd, attn1, row, adj, x, gpart, 0);

    // layer 2 (gather fuses the graph-mean reduction)
    k_proj<<<WB, 256, 0, stream>>>(x, W2_src, b2_src, W2_dst, b2_dst, fsh, fd);
    k_gather<<<N_NODES / 4, 256, 0, stream>>>(fsh, fd, attn2, row, adj, x, gpart, 1);

    k_final<<<1, 256, 0, stream>>>(gpart, Wh1, bh1, Wh2, bh2, (float*)d_out);
}

// Round 11
// 186.371 us; speedup vs baseline: 1.3033x; 1.0633x over previous
//
#include <hip/hip_runtime.h>
#include <hip/hip_bf16.h>

#define N_NODES 50000
#define N_EDGES 800000
#define DIM_IN 64
#define DIM_H 32
#define HEADS 4
#define NCLS 10
#define NEG 0.2f
#define NBUCK 196  // ceil(50000/256) buckets of 256 dst nodes
#define NPW 25     // nodes per wave in proj kernels (50000 = 2000 waves * 25)
#define FSCALE 16.0f  // fs/fd stored 16x (leaky is pos-homogeneous; attn/16)

typedef float floatx2 __attribute__((ext_vector_type(2)));

// ---------------- CSR build (binned, single-writer adj regions) ----------------

__global__ void k_bhist(const int* __restrict__ dst, int* __restrict__ bh) {
    __shared__ int lh[NBUCK];
    for (int i = threadIdx.x; i < NBUCK; i += 256) lh[i] = 0;
    __syncthreads();
    int base = blockIdx.x * 1024 + threadIdx.x;
#pragma unroll
    for (int r = 0; r < 4; r++) {
        int e = base + r * 256;
        if (e < N_EDGES) atomicAdd(&lh[dst[e] >> 8], 1);
    }
    __syncthreads();
    for (int i = threadIdx.x; i < NBUCK; i += 256) {
        int c = lh[i];
        if (c) atomicAdd(&bh[i], c);
    }
}

__global__ void k_bscan(const int* __restrict__ bh, int* __restrict__ bbase,
                        int* __restrict__ gcur) {
    __shared__ int s[256];
    int t = threadIdx.x;
    int v = (t < NBUCK) ? bh[t] : 0;
    s[t] = v;
    __syncthreads();
    for (int off = 1; off < 256; off <<= 1) {
        int u = (t >= off) ? s[t - off] : 0;
        __syncthreads();
        s[t] += u;
        __syncthreads();
    }
    int excl = s[t] - v;
    if (t < NBUCK) {
        bbase[t] = excl;
        gcur[t] = excl;
    }
    if (t == 0) bbase[NBUCK] = N_EDGES;
}

__global__ void k_bin(const int* __restrict__ src, const int* __restrict__ dst,
                      int* __restrict__ gcur, unsigned* __restrict__ stage) {
    __shared__ int lh[NBUCK], chunk[NBUCK];
    int t = threadIdx.x;
    for (int i = t; i < NBUCK; i += 256) lh[i] = 0;
    __syncthreads();
    int e0 = blockIdx.x * 4096;
    unsigned pk[16];
    int bk[16];
#pragma unroll
    for (int r = 0; r < 16; r++) {
        int e = e0 + r * 256 + t;
        bool ok = e < N_EDGES;
        int s = ok ? src[e] : 0;
        int d = ok ? dst[e] : 0;
        bk[r] = ok ? (d >> 8) : -1;
        pk[r] = (unsigned)s | ((unsigned)(d & 255) << 16);
        if (ok) atomicAdd(&lh[bk[r]], 1);
    }
    __syncthreads();
    for (int i = t; i < NBUCK; i += 256) {
        int c = lh[i];
        chunk[i] = c ? atomicAdd(&gcur[i], c) : 0;
        lh[i] = 0;  // reuse as local cursor
    }
    __syncthreads();
#pragma unroll
    for (int r = 0; r < 16; r++) {
        if (bk[r] >= 0) {
            int lp = atomicAdd(&lh[bk[r]], 1);
            stage[chunk[bk[r]] + lp] = pk[r];
        }
    }
}

__global__ void k_csr(const unsigned* __restrict__ stage, const int* __restrict__ bbase,
                      int* __restrict__ row, unsigned short* __restrict__ adj) {
    __shared__ int lcnt[256], lcur[256], sc[256];
    int b = blockIdx.x, t = threadIdx.x;
    int s0 = bbase[b], s1 = bbase[b + 1];
    lcnt[t] = 0;
    __syncthreads();
    for (int i = s0 + t; i < s1; i += 256) atomicAdd(&lcnt[stage[i] >> 16], 1);
    __syncthreads();
    int v = lcnt[t];
    sc[t] = v;
    __syncthreads();
    for (int off = 1; off < 256; off <<= 1) {
        int u = (t >= off) ? sc[t - off] : 0;
        __syncthreads();
        sc[t] += u;
        __syncthreads();
    }
    int excl = sc[t] - v;
    int n = b * 256 + t;
    if (n < N_NODES) row[n] = s0 + excl;
    if (b == NBUCK - 1 && t == 0) row[N_NODES] = N_EDGES;
    lcur[t] = s0 + excl;
    __syncthreads();
    for (int i = s0 + t; i < s1; i += 256) {
        unsigned p = stage[i];
        int pos = atomicAdd(&lcur[p >> 16], 1);
        adj[pos] = (unsigned short)(p & 0xFFFFu);  // src fits 16 bits
    }
}

// ---------------- layer-1: fused embed + projection ----------------
// Per node (low-rank, 10240 MACs): x = gf_row@W_in+b_in (64->32), then
// fs|fd = x@[W1s|W1d]+[b1s|b1d] (32->256), stored 16x-scaled; fs as fp8 e4m3.
__global__ __launch_bounds__(256, 2) void k_fused1(
    const float* __restrict__ gf, const float* __restrict__ W_in,
    const float* __restrict__ b_in, const float* __restrict__ W1s,
    const float* __restrict__ b1s, const float* __restrict__ W1d,
    const float* __restrict__ b1d, unsigned char* __restrict__ fsh,
    float* __restrict__ fd) {
    __shared__ float4 xb[4][2][8];  // [wave][dbuf][32 floats]
    int lane = threadIdx.x & 63;
    int wvl = threadIdx.x >> 6;
    int wave = (blockIdx.x * 256 + threadIdx.x) >> 6;
    int c = lane & 31, h = lane >> 5;
    int n0 = wave * NPW;
    if (n0 >= N_NODES) return;
    float wi[32];
#pragma unroll
    for (int k = 0; k < 32; k++) wi[k] = W_in[(h * 32 + k) * DIM_H + c];
    float bc = b_in[c];
    const float4* Wb = (lane < 32) ? (const float4*)W1s : (const float4*)W1d;
    const float4* bb = (lane < 32) ? (const float4*)b1s : (const float4*)b1d;
    float4 w[32];
#pragma unroll
    for (int k = 0; k < 32; k++) w[k] = Wb[k * 32 + c];
    float4 bias = bb[c];
#pragma unroll 2
    for (int i = 0; i < NPW; i++) {  // 50000 % 25 == 0: all nodes valid
        int nu = __builtin_amdgcn_readfirstlane(n0 + i);
        const float4* gr = (const float4*)(gf + (size_t)nu * DIM_IN + h * 32);
        float a1 = 0.f;
#pragma unroll
        for (int k4 = 0; k4 < 8; k4++) {
            float4 xv = gr[k4];
            a1 += xv.x * wi[k4 * 4 + 0];
            a1 += xv.y * wi[k4 * 4 + 1];
            a1 += xv.z * wi[k4 * 4 + 2];
            a1 += xv.w * wi[k4 * 4 + 3];
        }
        a1 += __shfl_xor(a1, 32, 64);
        if (lane < 32) ((float*)&xb[wvl][i & 1][0])[c] = a1 + bc;
        float4 acc = bias;
#pragma unroll
        for (int k4 = 0; k4 < 8; k4++) {
            float4 xv = xb[wvl][i & 1][k4];
#pragma unroll
            for (int j = 0; j < 4; j++) {
                float xk = (j == 0) ? xv.x : (j == 1) ? xv.y : (j == 2) ? xv.z : xv.w;
                float4 wk = w[k4 * 4 + j];
                acc.x += xk * wk.x;
                acc.y += xk * wk.y;
                acc.z += xk * wk.z;
                acc.w += xk * wk.w;
            }
        }
        if (lane < 32) {
            int pk = __builtin_amdgcn_cvt_pk_fp8_f32(acc.x * FSCALE, acc.y * FSCALE,
                                                     0, false);
            pk = __builtin_amdgcn_cvt_pk_fp8_f32(acc.z * FSCALE, acc.w * FSCALE,
                                                 pk, true);
            *(int*)&fsh[(size_t)nu * 128 + c * 4] = pk;
        } else {
            float4 o;
            o.x = acc.x * FSCALE;
            o.y = acc.y * FSCALE;
            o.z = acc.z * FSCALE;
            o.w = acc.w * FSCALE;
            *(float4*)&fd[(size_t)nu * 128 + c * 4] = o;
        }
    }
}

// ---------------- layer-2 projection (weights-in-registers) ----------------
__global__ __launch_bounds__(256, 2) void k_proj(
    const float* __restrict__ x, const float* __restrict__ Wsrc,
    const float* __restrict__ bsrc, const float* __restrict__ Wdst,
    const float* __restrict__ bdst, unsigned char* __restrict__ fsh,
    float* __restrict__ fd) {
    int lane = threadIdx.x & 63;
    int wave = (blockIdx.x * 256 + threadIdx.x) >> 6;
    int cl = lane & 31;
    int n0 = wave * NPW;
    if (n0 >= N_NODES) return;
    const float4* Wb = (lane < 32) ? (const float4*)Wsrc : (const float4*)Wdst;
    const float4* bb = (lane < 32) ? (const float4*)bsrc : (const float4*)bdst;
    float4 w[32];
#pragma unroll
    for (int k = 0; k < 32; k++) w[k] = Wb[k * 32 + cl];
    float4 bias = bb[cl];
#pragma unroll 2
    for (int i = 0; i < NPW; i++) {
        int nu = __builtin_amdgcn_readfirstlane(n0 + i);
        const float4* xr = (const float4*)(x + (size_t)nu * DIM_H);
        float4 acc = bias;
#pragma unroll
        for (int k4 = 0; k4 < 8; k4++) {
            float4 xv = xr[k4];
#pragma unroll
            for (int j = 0; j < 4; j++) {
                float xk = (j == 0) ? xv.x : (j == 1) ? xv.y : (j == 2) ? xv.z : xv.w;
                float4 wk = w[k4 * 4 + j];
                acc.x += xk * wk.x;
                acc.y += xk * wk.y;
                acc.z += xk * wk.z;
                acc.w += xk * wk.w;
            }
        }
        if (lane < 32) {
            int pk = __builtin_amdgcn_cvt_pk_fp8_f32(acc.x * FSCALE, acc.y * FSCALE,
                                                     0, false);
            pk = __builtin_amdgcn_cvt_pk_fp8_f32(acc.z * FSCALE, acc.w * FSCALE,
                                                 pk, true);
            *(int*)&fsh[(size_t)nu * 128 + cl * 4] = pk;
        } else {
            float4 o;
            o.x = acc.x * FSCALE;
            o.y = acc.y * FSCALE;
            o.z = acc.z * FSCALE;
            o.w = acc.w * FSCALE;
            *(float4*)&fd[(size_t)nu * 128 + cl * 4] = o;
        }
    }
}

// ---------------- GAT gather (fp8 rows, 2 edges per wave-instruction) -------
// One wave per destination node. Lane = (e2=lane>>5, sub=lane&31). Lane owns
// dims sub*4..+3 of its edge's 128B fp8 row: one dword (4B) load; unpack via
// v_cvt_pk_f32_fp8. Head h=sub>>3 (8 lanes): score reduce = 3 shfl_xor.
// fs/fd are 16x-scaled; attn pre-divided by 16 -> scores exact; output
// rescaled by folding 0.25/16 into inv. Softmax shift dropped.
__device__ __forceinline__ void pair_acc(unsigned u, const float4& fdv,
                                         const float4& a4, float4& acc, float& den,
                                         bool valid) {
    floatx2 f01 = __builtin_amdgcn_cvt_pk_f32_fp8((int)u, false);
    floatx2 f23 = __builtin_amdgcn_cvt_pk_f32_fp8((int)u, true);
    float t0 = f01.x + fdv.x; t0 = fmaxf(t0, NEG * t0);
    float t1 = f01.y + fdv.y; t1 = fmaxf(t1, NEG * t1);
    float t2 = f23.x + fdv.z; t2 = fmaxf(t2, NEG * t2);
    float t3 = f23.y + fdv.w; t3 = fmaxf(t3, NEG * t3);
    float p = t0 * a4.x + t1 * a4.y + t2 * a4.z + t3 * a4.w;
    p += __shfl_xor(p, 1, 64);
    p += __shfl_xor(p, 2, 64);
    p += __shfl_xor(p, 4, 64);
    float w = __expf(p);
    if (!valid) w = 0.f;
    den += w;
    acc.x += w * f01.x;
    acc.y += w * f01.y;
    acc.z += w * f23.x;
    acc.w += w * f23.y;
}

__global__ void k_gather(const unsigned char* __restrict__ fsh,
                         const float* __restrict__ fd, const float* __restrict__ attn,
                         const int* __restrict__ row,
                         const unsigned short* __restrict__ adj,
                         float* __restrict__ xout, float* __restrict__ gpart,
                         int mode) {  // mode 0: relu + store x; 1: graph-mean reduce
    __shared__ float bsum[32];
    int tid = threadIdx.x;
    if (mode) {
        if (tid < 32) bsum[tid] = 0.f;
        __syncthreads();
    }
    int wave = tid >> 6;
    int lane = tid & 63;
    int n = blockIdx.x * 4 + wave;  // 50000 = 12500 * 4: always valid
    int sub = lane & 31, e2 = lane >> 5;
    unsigned suboff = (unsigned)sub << 2;  // 4B per lane within 128B row
    float4 a4 = ((const float4*)attn)[sub];
    a4.x *= (1.f / FSCALE);
    a4.y *= (1.f / FSCALE);
    a4.z *= (1.f / FSCALE);
    a4.w *= (1.f / FSCALE);
    float4 fdv = ((const float4*)(fd + (size_t)n * 128))[sub];
    float4 acc = {0.f, 0.f, 0.f, 0.f};
    float den = 0.f;
    int beg = row[n], end = row[n + 1];
    for (int base = beg; base < end; base += 64) {
        int m = end - base;
        if (m > 64) m = 64;
        int myadj = (lane < m) ? (int)adj[base + lane] : 0;
        int j = 0;
        for (; j + 8 <= m; j += 8) {  // 4 pair-slots = 8 edges, 4 loads in flight
            unsigned o0 = ((unsigned)__shfl(myadj, j + 0 + e2, 64) << 7) + suboff;
            unsigned o1 = ((unsigned)__shfl(myadj, j + 2 + e2, 64) << 7) + suboff;
            unsigned o2 = ((unsigned)__shfl(myadj, j + 4 + e2, 64) << 7) + suboff;
            unsigned o3 = ((unsigned)__shfl(myadj, j + 6 + e2, 64) << 7) + suboff;
            unsigned u0 = *(const unsigned*)(fsh + o0);
            unsigned u1 = *(const unsigned*)(fsh + o1);
            unsigned u2 = *(const unsigned*)(fsh + o2);
            unsigned u3 = *(const unsigned*)(fsh + o3);
            pair_acc(u0, fdv, a4, acc, den, true);
            pair_acc(u1, fdv, a4, acc, den, true);
            pair_acc(u2, fdv, a4, acc, den, true);
            pair_acc(u3, fdv, a4, acc, den, true);
        }
        for (; j < m; j += 2) {  // tail pairs (possibly half-valid)
            int idx = j + e2;
            bool valid = idx < m;
            unsigned o = ((unsigned)__shfl(myadj, valid ? idx : j, 64) << 7) + suboff;
            unsigned u = *(const unsigned*)(fsh + o);
            pair_acc(u, fdv, a4, acc, den, valid);
        }
    }
    // combine edge-parity halves
    den += __shfl_xor(den, 32, 64);
    acc.x += __shfl_xor(acc.x, 32, 64);
    acc.y += __shfl_xor(acc.y, 32, 64);
    acc.z += __shfl_xor(acc.z, 32, 64);
    acc.w += __shfl_xor(acc.w, 32, 64);
    float inv = den > 0.f ? (0.25f / FSCALE) / den : 0.f;  // head-mean + unscale
    float4 o;
    o.x = acc.x * inv;
    o.y = acc.y * inv;
    o.z = acc.z * inv;
    o.w = acc.w * inv;
    // head mean: sum over sub^8, sub^16
    o.x += __shfl_xor(o.x, 8, 64);
    o.y += __shfl_xor(o.y, 8, 64);
    o.z += __shfl_xor(o.z, 8, 64);
    o.w += __shfl_xor(o.w, 8, 64);
    o.x += __shfl_xor(o.x, 16, 64);
    o.y += __shfl_xor(o.y, 16, 64);
    o.z += __shfl_xor(o.z, 16, 64);
    o.w += __shfl_xor(o.w, 16, 64);
    if (mode == 0) {
        if (lane < 8) {
            o.x = fmaxf(o.x, 0.f);
            o.y = fmaxf(o.y, 0.f);
            o.z = fmaxf(o.z, 0.f);
            o.w = fmaxf(o.w, 0.f);
            ((float4*)(xout + (size_t)n * 32))[lane] = o;
        }
    } else {
        if (lane < 8) {
            atomicAdd(&bsum[lane * 4 + 0], o.x);
            atomicAdd(&bsum[lane * 4 + 1], o.y);
            atomicAdd(&bsum[lane * 4 + 2], o.z);
            atomicAdd(&bsum[lane * 4 + 3], o.w);
        }
        __syncthreads();
        if (tid < 32) atomicAdd(&gpart[(blockIdx.x & 63) * 32 + tid], bsum[tid]);
    }
}

__global__ void k_final(const float* __restrict__ gpart, const float* __restrict__ Wh1,
                        const float* __restrict__ bh1, const float* __restrict__ Wh2,
                        const float* __restrict__ bh2, float* __restrict__ out) {
    __shared__ float gv[32], gh[32], lg[16];
    int t = threadIdx.x;
    if (t < 32) {
        float s = 0.f;
        for (int b = 0; b < 64; b++) s += gpart[b * 32 + t];
        gv[t] = s * (1.f / (float)N_NODES);
    }
    __syncthreads();
    if (t < 32) {
        float s = bh1[t];
        for (int d = 0; d < 32; d++) s += gv[d] * Wh1[d * 32 + t];
        gh[t] = s > 0.f ? s : 0.f;
    }
    __syncthreads();
    if (t < NCLS) {
        float s = bh2[t];
        for (int j = 0; j < 32; j++) s += gh[j] * Wh2[j * NCLS + t];
        lg[t] = s;
    }
    __syncthreads();
    if (t == 0) {
        float m = lg[0];
        for (int c = 1; c < NCLS; c++) m = fmaxf(m, lg[c]);
        float ex[NCLS], sum = 0.f;
        for (int c = 0; c < NCLS; c++) {
            ex[c] = __expf(lg[c] - m);
            sum += ex[c];
        }
        float inv = 1.f / sum;
        for (int c = 0; c < NCLS; c++) out[c] = ex[c] * inv;
    }
}

extern "C" void kernel_launch(void* const* d_in, const int* in_sizes, int n_in,
                              void* d_out, int out_size, void* d_ws, size_t ws_size,
                              hipStream_t stream) {
    const float* g_feats = (const float*)d_in[0];
    const int* edge_src = (const int*)d_in[1];
    const int* edge_dst = (const int*)d_in[2];
    const float* W_in = (const float*)d_in[3];
    const float* b_in = (const float*)d_in[4];
    const float* W1_src = (const float*)d_in[5];
    const float* b1_src = (const float*)d_in[6];
    const float* W1_dst = (const float*)d_in[7];
    const float* b1_dst = (const float*)d_in[8];
    const float* attn1 = (const float*)d_in[9];
    const float* W2_src = (const float*)d_in[10];
    const float* b2_src = (const float*)d_in[11];
    const float* W2_dst = (const float*)d_in[12];
    const float* b2_dst = (const float*)d_in[13];
    const float* attn2 = (const float*)d_in[14];
    const float* Wh1 = (const float*)d_in[15];
    const float* bh1 = (const float*)d_in[16];
    const float* Wh2 = (const float*)d_in[17];
    const float* bh2 = (const float*)d_in[18];

    // workspace layout
    float* x = (float*)d_ws;                                      // N*32 f32
    unsigned char* fsh = (unsigned char*)(x + (size_t)N_NODES * 32);  // N*128 fp8
    float* fd = (float*)(fsh + (size_t)N_NODES * 128);            // N*128 f32 (16x)
    float* gpart = fd + (size_t)N_NODES * 128;                    // 64*32
    int* bh = (int*)(gpart + 64 * 32);                            // NBUCK
    int* bbase = bh + NBUCK;                                      // NBUCK+1
    int* gcur = bbase + NBUCK + 1;                                // NBUCK
    int* row = gcur + NBUCK;                                      // N+1
    unsigned* stage = (unsigned*)(row + N_NODES + 1);             // E
    unsigned short* adj = (unsigned short*)(stage + N_EDGES);     // E u16

    const int WB = (N_NODES / NPW + 3) / 4;  // 500 blocks: 4 waves x 25 nodes

    // zero gpart + bucket histogram in one memset (adjacent)
    hipMemsetAsync(gpart, 0, (64 * 32 + NBUCK) * sizeof(int), stream);

    // CSR build (binned)
    k_bhist<<<(N_EDGES + 1023) / 1024, 256, 0, stream>>>(edge_dst, bh);
    k_bscan<<<1, 256, 0, stream>>>(bh, bbase, gcur);
    k_bin<<<(N_EDGES + 4095) / 4096, 256, 0, stream>>>(edge_src, edge_dst, gcur, stage);
    k_csr<<<NBUCK, 256, 0, stream>>>(stage, bbase, row, adj);

    // layer 1 (pipeline-fused embed+proj, low-rank path)
    k_fused1<<<WB, 256, 0, stream>>>(g_feats, W_in, b_in, W1_src, b1_src, W1_dst,
                                     b1_dst, fsh, fd);
    k_gather<<<N_NODES / 4, 256, 0, stream>>>(fsh, fd, attn1, row, adj, x, gpart, 0);

    // layer 2 (gather fuses the graph-mean reduction)
    k_proj<<<WB, 256, 0, stream>>>(x, W2_src, b2_src, W2_dst, b2_dst, fsh, fd);
    k_gather<<<N_NODES / 4, 256, 0, stream>>>(fsh, fd, attn2, row, adj, x, gpart, 1);

    k_final<<<1, 256, 0, stream>>>(gpart, Wh1, bh1, Wh2, bh2, (float*)d_out);
}

// Round 12
// 184.154 us; speedup vs baseline: 1.3190x; 1.0120x over previous
//
#include <hip/hip_runtime.h>
#include <hip/hip_bf16.h>

#define N_NODES 50000
#define N_EDGES 800000
#define DIM_IN 64
#define DIM_H 32
#define HEADS 4
#define NCLS 10
#define NEG 0.2f
#define NBUCK 196  // ceil(50000/256) buckets of 256 dst nodes
#define NPW 25     // nodes per wave in proj kernels (50000 = 2000 waves * 25)
#define FSCALE 16.0f  // fs/fd stored 16x (leaky is pos-homogeneous; attn/16)
#define LOG2E 1.44269504088896f

typedef float floatx2 __attribute__((ext_vector_type(2)));

__device__ __forceinline__ float fast_exp2(float x) {
#if __has_builtin(__builtin_amdgcn_exp2f)
    return __builtin_amdgcn_exp2f(x);
#else
    return __expf(x * 0.69314718055994531f);
#endif
}

// ---------------- CSR build (binned, single-writer adj regions) ----------------

__global__ void k_bhist(const int* __restrict__ dst, int* __restrict__ bh) {
    __shared__ int lh[NBUCK];
    for (int i = threadIdx.x; i < NBUCK; i += 256) lh[i] = 0;
    __syncthreads();
    int base = blockIdx.x * 1024 + threadIdx.x;
#pragma unroll
    for (int r = 0; r < 4; r++) {
        int e = base + r * 256;
        if (e < N_EDGES) atomicAdd(&lh[dst[e] >> 8], 1);
    }
    __syncthreads();
    for (int i = threadIdx.x; i < NBUCK; i += 256) {
        int c = lh[i];
        if (c) atomicAdd(&bh[i], c);
    }
}

__global__ void k_bscan(const int* __restrict__ bh, int* __restrict__ bbase,
                        int* __restrict__ gcur) {
    __shared__ int s[256];
    int t = threadIdx.x;
    int v = (t < NBUCK) ? bh[t] : 0;
    s[t] = v;
    __syncthreads();
    for (int off = 1; off < 256; off <<= 1) {
        int u = (t >= off) ? s[t - off] : 0;
        __syncthreads();
        s[t] += u;
        __syncthreads();
    }
    int excl = s[t] - v;
    if (t < NBUCK) {
        bbase[t] = excl;
        gcur[t] = excl;
    }
    if (t == 0) bbase[NBUCK] = N_EDGES;
}

__global__ void k_bin(const int* __restrict__ src, const int* __restrict__ dst,
                      int* __restrict__ gcur, unsigned* __restrict__ stage) {
    __shared__ int lh[NBUCK], chunk[NBUCK];
    int t = threadIdx.x;
    for (int i = t; i < NBUCK; i += 256) lh[i] = 0;
    __syncthreads();
    int e0 = blockIdx.x * 4096;
    unsigned pk[16];
    int bk[16];
#pragma unroll
    for (int r = 0; r < 16; r++) {
        int e = e0 + r * 256 + t;
        bool ok = e < N_EDGES;
        int s = ok ? src[e] : 0;
        int d = ok ? dst[e] : 0;
        bk[r] = ok ? (d >> 8) : -1;
        pk[r] = (unsigned)s | ((unsigned)(d & 255) << 16);
        if (ok) atomicAdd(&lh[bk[r]], 1);
    }
    __syncthreads();
    for (int i = t; i < NBUCK; i += 256) {
        int c = lh[i];
        chunk[i] = c ? atomicAdd(&gcur[i], c) : 0;
        lh[i] = 0;  // reuse as local cursor
    }
    __syncthreads();
#pragma unroll
    for (int r = 0; r < 16; r++) {
        if (bk[r] >= 0) {
            int lp = atomicAdd(&lh[bk[r]], 1);
            stage[chunk[bk[r]] + lp] = pk[r];
        }
    }
}

__global__ void k_csr(const unsigned* __restrict__ stage, const int* __restrict__ bbase,
                      int* __restrict__ row, unsigned short* __restrict__ adj) {
    __shared__ int lcnt[256], lcur[256], sc[256];
    int b = blockIdx.x, t = threadIdx.x;
    int s0 = bbase[b], s1 = bbase[b + 1];
    lcnt[t] = 0;
    __syncthreads();
    for (int i = s0 + t; i < s1; i += 256) atomicAdd(&lcnt[stage[i] >> 16], 1);
    __syncthreads();
    int v = lcnt[t];
    sc[t] = v;
    __syncthreads();
    for (int off = 1; off < 256; off <<= 1) {
        int u = (t >= off) ? sc[t - off] : 0;
        __syncthreads();
        sc[t] += u;
        __syncthreads();
    }
    int excl = sc[t] - v;
    int n = b * 256 + t;
    if (n < N_NODES) row[n] = s0 + excl;
    if (b == NBUCK - 1 && t == 0) row[N_NODES] = N_EDGES;
    lcur[t] = s0 + excl;
    __syncthreads();
    for (int i = s0 + t; i < s1; i += 256) {
        unsigned p = stage[i];
        int pos = atomicAdd(&lcur[p >> 16], 1);
        adj[pos] = (unsigned short)(p & 0xFFFFu);  // src fits 16 bits
    }
}

// ---------------- helpers ----------------

__device__ __forceinline__ unsigned short f2bf(float v) {  // RTN f32->bf16
    unsigned u = __builtin_bit_cast(unsigned, v);
    u += 0x7FFFu + ((u >> 16) & 1u);
    return (unsigned short)(u >> 16);
}
__device__ __forceinline__ float bf2f(unsigned short h) {
    return __builtin_bit_cast(float, (unsigned)h << 16);
}

// ---------------- layer-1: fused embed + projection ----------------
// Per node (low-rank, 10240 MACs): x = gf_row@W_in+b_in (64->32), then
// fs|fd = x@[W1s|W1d]+[b1s|b1d] (32->256), stored 16x-scaled; fs fp8, fd bf16.
__global__ __launch_bounds__(256, 2) void k_fused1(
    const float* __restrict__ gf, const float* __restrict__ W_in,
    const float* __restrict__ b_in, const float* __restrict__ W1s,
    const float* __restrict__ b1s, const float* __restrict__ W1d,
    const float* __restrict__ b1d, unsigned char* __restrict__ fsh,
    unsigned short* __restrict__ fdh) {
    __shared__ float4 xb[4][2][8];  // [wave][dbuf][32 floats]
    int lane = threadIdx.x & 63;
    int wvl = threadIdx.x >> 6;
    int wave = (blockIdx.x * 256 + threadIdx.x) >> 6;
    int c = lane & 31, h = lane >> 5;
    int n0 = wave * NPW;
    if (n0 >= N_NODES) return;
    float wi[32];
#pragma unroll
    for (int k = 0; k < 32; k++) wi[k] = W_in[(h * 32 + k) * DIM_H + c];
    float bc = b_in[c];
    const float4* Wb = (lane < 32) ? (const float4*)W1s : (const float4*)W1d;
    const float4* bb = (lane < 32) ? (const float4*)b1s : (const float4*)b1d;
    float4 w[32];
#pragma unroll
    for (int k = 0; k < 32; k++) w[k] = Wb[k * 32 + c];
    float4 bias = bb[c];
#pragma unroll 2
    for (int i = 0; i < NPW; i++) {  // 50000 % 25 == 0: all nodes valid
        int nu = __builtin_amdgcn_readfirstlane(n0 + i);
        const float4* gr = (const float4*)(gf + (size_t)nu * DIM_IN + h * 32);
        float a1 = 0.f;
#pragma unroll
        for (int k4 = 0; k4 < 8; k4++) {
            float4 xv = gr[k4];
            a1 += xv.x * wi[k4 * 4 + 0];
            a1 += xv.y * wi[k4 * 4 + 1];
            a1 += xv.z * wi[k4 * 4 + 2];
            a1 += xv.w * wi[k4 * 4 + 3];
        }
        a1 += __shfl_xor(a1, 32, 64);
        if (lane < 32) ((float*)&xb[wvl][i & 1][0])[c] = a1 + bc;
        float4 acc = bias;
#pragma unroll
        for (int k4 = 0; k4 < 8; k4++) {
            float4 xv = xb[wvl][i & 1][k4];
#pragma unroll
            for (int j = 0; j < 4; j++) {
                float xk = (j == 0) ? xv.x : (j == 1) ? xv.y : (j == 2) ? xv.z : xv.w;
                float4 wk = w[k4 * 4 + j];
                acc.x += xk * wk.x;
                acc.y += xk * wk.y;
                acc.z += xk * wk.z;
                acc.w += xk * wk.w;
            }
        }
        if (lane < 32) {
            int pk = __builtin_amdgcn_cvt_pk_fp8_f32(acc.x * FSCALE, acc.y * FSCALE,
                                                     0, false);
            pk = __builtin_amdgcn_cvt_pk_fp8_f32(acc.z * FSCALE, acc.w * FSCALE,
                                                 pk, true);
            *(int*)&fsh[(size_t)nu * 128 + c * 4] = pk;
        } else {
            ushort4 o;
            o.x = f2bf(acc.x * FSCALE);
            o.y = f2bf(acc.y * FSCALE);
            o.z = f2bf(acc.z * FSCALE);
            o.w = f2bf(acc.w * FSCALE);
            *(ushort4*)&fdh[(size_t)nu * 128 + c * 4] = o;
        }
    }
}

// ---------------- layer-2 projection (weights-in-registers) ----------------
__global__ __launch_bounds__(256, 2) void k_proj(
    const float* __restrict__ x, const float* __restrict__ Wsrc,
    const float* __restrict__ bsrc, const float* __restrict__ Wdst,
    const float* __restrict__ bdst, unsigned char* __restrict__ fsh,
    unsigned short* __restrict__ fdh) {
    int lane = threadIdx.x & 63;
    int wave = (blockIdx.x * 256 + threadIdx.x) >> 6;
    int cl = lane & 31;
    int n0 = wave * NPW;
    if (n0 >= N_NODES) return;
    const float4* Wb = (lane < 32) ? (const float4*)Wsrc : (const float4*)Wdst;
    const float4* bb = (lane < 32) ? (const float4*)bsrc : (const float4*)bdst;
    float4 w[32];
#pragma unroll
    for (int k = 0; k < 32; k++) w[k] = Wb[k * 32 + cl];
    float4 bias = bb[cl];
#pragma unroll 2
    for (int i = 0; i < NPW; i++) {
        int nu = __builtin_amdgcn_readfirstlane(n0 + i);
        const float4* xr = (const float4*)(x + (size_t)nu * DIM_H);
        float4 acc = bias;
#pragma unroll
        for (int k4 = 0; k4 < 8; k4++) {
            float4 xv = xr[k4];
#pragma unroll
            for (int j = 0; j < 4; j++) {
                float xk = (j == 0) ? xv.x : (j == 1) ? xv.y : (j == 2) ? xv.z : xv.w;
                float4 wk = w[k4 * 4 + j];
                acc.x += xk * wk.x;
                acc.y += xk * wk.y;
                acc.z += xk * wk.z;
                acc.w += xk * wk.w;
            }
        }
        if (lane < 32) {
            int pk = __builtin_amdgcn_cvt_pk_fp8_f32(acc.x * FSCALE, acc.y * FSCALE,
                                                     0, false);
            pk = __builtin_amdgcn_cvt_pk_fp8_f32(acc.z * FSCALE, acc.w * FSCALE,
                                                 pk, true);
            *(int*)&fsh[(size_t)nu * 128 + cl * 4] = pk;
        } else {
            ushort4 o;
            o.x = f2bf(acc.x * FSCALE);
            o.y = f2bf(acc.y * FSCALE);
            o.z = f2bf(acc.z * FSCALE);
            o.w = f2bf(acc.w * FSCALE);
            *(ushort4*)&fdh[(size_t)nu * 128 + cl * 4] = o;
        }
    }
}

// ---------------- GAT gather (fp8 rows, packed-f32 math) ----------------
// One wave per destination node. Lane = (e2=lane>>5, sub=lane&31). Lane owns
// dims sub*4..+3 of its edge's 128B fp8 row: one dword load, unpacked by
// v_cvt_pk_f32_fp8. floatx2 ops -> v_pk_{add,mul,fma}_f32. Head h=sub>>3:
// score reduce = 3 shfl_xor over 8 lanes. attn prescaled by log2e/16 so
// w = v_exp (base-2) directly. fs/fd 16x-scaled; 0.25/16 folded into inv.
__device__ __forceinline__ void pair_acc(unsigned u, floatx2 fd01, floatx2 fd23,
                                         floatx2 a01, floatx2 a23, floatx2& acc01,
                                         floatx2& acc23, float& den, bool valid) {
    floatx2 f01 = __builtin_amdgcn_cvt_pk_f32_fp8((int)u, false);
    floatx2 f23 = __builtin_amdgcn_cvt_pk_f32_fp8((int)u, true);
    floatx2 t01 = f01 + fd01;
    floatx2 t23 = f23 + fd23;
    floatx2 n01 = t01 * NEG;
    floatx2 n23 = t23 * NEG;
    floatx2 l01, l23;
    l01.x = fmaxf(t01.x, n01.x);
    l01.y = fmaxf(t01.y, n01.y);
    l23.x = fmaxf(t23.x, n23.x);
    l23.y = fmaxf(t23.y, n23.y);
    floatx2 d = l01 * a01 + l23 * a23;  // pk_mul + pk_fma
    float p = d.x + d.y;
    p += __shfl_xor(p, 1, 64);
    p += __shfl_xor(p, 2, 64);
    p += __shfl_xor(p, 4, 64);
    float w = fast_exp2(p);
    if (!valid) w = 0.f;
    den += w;
    floatx2 wv = {w, w};
    acc01 += wv * f01;
    acc23 += wv * f23;
}

__global__ void k_gather(const unsigned char* __restrict__ fsh,
                         const unsigned short* __restrict__ fdh,
                         const float* __restrict__ attn, const int* __restrict__ row,
                         const unsigned short* __restrict__ adj,
                         float* __restrict__ xout, float* __restrict__ gpart,
                         int mode) {  // mode 0: relu + store x; 1: graph-mean reduce
    __shared__ float bsum[32];
    int tid = threadIdx.x;
    if (mode) {
        if (tid < 32) bsum[tid] = 0.f;
        __syncthreads();
    }
    int wave = tid >> 6;
    int lane = tid & 63;
    int n = blockIdx.x * 4 + wave;  // 50000 = 12500 * 4: always valid
    int sub = lane & 31, e2 = lane >> 5;
    unsigned suboff = (unsigned)sub << 2;  // 4B per lane within 128B row
    float4 a4 = ((const float4*)attn)[sub];
    const float asc = LOG2E / FSCALE;
    floatx2 a01 = {a4.x * asc, a4.y * asc};
    floatx2 a23 = {a4.z * asc, a4.w * asc};
    ushort4 fdu = *(const ushort4*)(fdh + (size_t)n * 128 + sub * 4);
    floatx2 fd01 = {bf2f(fdu.x), bf2f(fdu.y)};
    floatx2 fd23 = {bf2f(fdu.z), bf2f(fdu.w)};
    floatx2 acc01 = {0.f, 0.f}, acc23 = {0.f, 0.f};
    float den = 0.f;
    int beg = row[n], end = row[n + 1];
    for (int base = beg; base < end; base += 64) {
        int m = end - base;
        if (m > 64) m = 64;
        int myadj = (lane < m) ? (int)adj[base + lane] : 0;
        int j = 0;
        for (; j + 16 <= m; j += 16) {  // 8 pair-slots = 16 edges, 8 loads in flight
            unsigned o0 = ((unsigned)__shfl(myadj, j + 0 + e2, 64) << 7) + suboff;
            unsigned o1 = ((unsigned)__shfl(myadj, j + 2 + e2, 64) << 7) + suboff;
            unsigned o2 = ((unsigned)__shfl(myadj, j + 4 + e2, 64) << 7) + suboff;
            unsigned o3 = ((unsigned)__shfl(myadj, j + 6 + e2, 64) << 7) + suboff;
            unsigned o4 = ((unsigned)__shfl(myadj, j + 8 + e2, 64) << 7) + suboff;
            unsigned o5 = ((unsigned)__shfl(myadj, j + 10 + e2, 64) << 7) + suboff;
            unsigned o6 = ((unsigned)__shfl(myadj, j + 12 + e2, 64) << 7) + suboff;
            unsigned o7 = ((unsigned)__shfl(myadj, j + 14 + e2, 64) << 7) + suboff;
            unsigned u0 = *(const unsigned*)(fsh + o0);
            unsigned u1 = *(const unsigned*)(fsh + o1);
            unsigned u2 = *(const unsigned*)(fsh + o2);
            unsigned u3 = *(const unsigned*)(fsh + o3);
            unsigned u4 = *(const unsigned*)(fsh + o4);
            unsigned u5 = *(const unsigned*)(fsh + o5);
            unsigned u6 = *(const unsigned*)(fsh + o6);
            unsigned u7 = *(const unsigned*)(fsh + o7);
            pair_acc(u0, fd01, fd23, a01, a23, acc01, acc23, den, true);
            pair_acc(u1, fd01, fd23, a01, a23, acc01, acc23, den, true);
            pair_acc(u2, fd01, fd23, a01, a23, acc01, acc23, den, true);
            pair_acc(u3, fd01, fd23, a01, a23, acc01, acc23, den, true);
            pair_acc(u4, fd01, fd23, a01, a23, acc01, acc23, den, true);
            pair_acc(u5, fd01, fd23, a01, a23, acc01, acc23, den, true);
            pair_acc(u6, fd01, fd23, a01, a23, acc01, acc23, den, true);
            pair_acc(u7, fd01, fd23, a01, a23, acc01, acc23, den, true);
        }
        for (; j + 8 <= m; j += 8) {  // 4 pair-slots = 8 edges
            unsigned o0 = ((unsigned)__shfl(myadj, j + 0 + e2, 64) << 7) + suboff;
            unsigned o1 = ((unsigned)__shfl(myadj, j + 2 + e2, 64) << 7) + suboff;
            unsigned o2 = ((unsigned)__shfl(myadj, j + 4 + e2, 64) << 7) + suboff;
            unsigned o3 = ((unsigned)__shfl(myadj, j + 6 + e2, 64) << 7) + suboff;
            unsigned u0 = *(const unsigned*)(fsh + o0);
            unsigned u1 = *(const unsigned*)(fsh + o1);
            unsigned u2 = *(const unsigned*)(fsh + o2);
            unsigned u3 = *(const unsigned*)(fsh + o3);
            pair_acc(u0, fd01, fd23, a01, a23, acc01, acc23, den, true);
            pair_acc(u1, fd01, fd23, a01, a23, acc01, acc23, den, true);
            pair_acc(u2, fd01, fd23, a01, a23, acc01, acc23, den, true);
            pair_acc(u3, fd01, fd23, a01, a23, acc01, acc23, den, true);
        }
        for (; j < m; j += 2) {  // tail pairs (possibly half-valid)
            int idx = j + e2;
            bool valid = idx < m;
            unsigned o = ((unsigned)__shfl(myadj, valid ? idx : j, 64) << 7) + suboff;
            unsigned u = *(const unsigned*)(fsh + o);
            pair_acc(u, fd01, fd23, a01, a23, acc01, acc23, den, valid);
        }
    }
    // combine edge-parity halves
    den += __shfl_xor(den, 32, 64);
    float ax = acc01.x, ay = acc01.y, az = acc23.x, aw = acc23.y;
    ax += __shfl_xor(ax, 32, 64);
    ay += __shfl_xor(ay, 32, 64);
    az += __shfl_xor(az, 32, 64);
    aw += __shfl_xor(aw, 32, 64);
    float inv = den > 0.f ? (0.25f / FSCALE) / den : 0.f;  // head-mean + unscale
    float4 o;
    o.x = ax * inv;
    o.y = ay * inv;
    o.z = az * inv;
    o.w = aw * inv;
    // head mean: sum over sub^8, sub^16
    o.x += __shfl_xor(o.x, 8, 64);
    o.y += __shfl_xor(o.y, 8, 64);
    o.z += __shfl_xor(o.z, 8, 64);
    o.w += __shfl_xor(o.w, 8, 64);
    o.x += __shfl_xor(o.x, 16, 64);
    o.y += __shfl_xor(o.y, 16, 64);
    o.z += __shfl_xor(o.z, 16, 64);
    o.w += __shfl_xor(o.w, 16, 64);
    if (mode == 0) {
        if (lane < 8) {
            o.x = fmaxf(o.x, 0.f);
            o.y = fmaxf(o.y, 0.f);
            o.z = fmaxf(o.z, 0.f);
            o.w = fmaxf(o.w, 0.f);
            ((float4*)(xout + (size_t)n * 32))[lane] = o;
        }
    } else {
        if (lane < 8) {
            atomicAdd(&bsum[lane * 4 + 0], o.x);
            atomicAdd(&bsum[lane * 4 + 1], o.y);
            atomicAdd(&bsum[lane * 4 + 2], o.z);
            atomicAdd(&bsum[lane * 4 + 3], o.w);
        }
        __syncthreads();
        if (tid < 32) atomicAdd(&gpart[(blockIdx.x & 63) * 32 + tid], bsum[tid]);
    }
}

__global__ void k_final(const float* __restrict__ gpart, const float* __restrict__ Wh1,
                        const float* __restrict__ bh1, const float* __restrict__ Wh2,
                        const float* __restrict__ bh2, float* __restrict__ out) {
    __shared__ float gv[32], gh[32], lg[16];
    int t = threadIdx.x;
    if (t < 32) {
        float s = 0.f;
        for (int b = 0; b < 64; b++) s += gpart[b * 32 + t];
        gv[t] = s * (1.f / (float)N_NODES);
    }
    __syncthreads();
    if (t < 32) {
        float s = bh1[t];
        for (int d = 0; d < 32; d++) s += gv[d] * Wh1[d * 32 + t];
        gh[t] = s > 0.f ? s : 0.f;
    }
    __syncthreads();
    if (t < NCLS) {
        float s = bh2[t];
        for (int j = 0; j < 32; j++) s += gh[j] * Wh2[j * NCLS + t];
        lg[t] = s;
    }
    __syncthreads();
    if (t == 0) {
        float m = lg[0];
        for (int c = 1; c < NCLS; c++) m = fmaxf(m, lg[c]);
        float ex[NCLS], sum = 0.f;
        for (int c = 0; c < NCLS; c++) {
            ex[c] = __expf(lg[c] - m);
            sum += ex[c];
        }
        float inv = 1.f / sum;
        for (int c = 0; c < NCLS; c++) out[c] = ex[c] * inv;
    }
}

extern "C" void kernel_launch(void* const* d_in, const int* in_sizes, int n_in,
                              void* d_out, int out_size, void* d_ws, size_t ws_size,
                              hipStream_t stream) {
    const float* g_feats = (const float*)d_in[0];
    const int* edge_src = (const int*)d_in[1];
    const int* edge_dst = (const int*)d_in[2];
    const float* W_in = (const float*)d_in[3];
    const float* b_in = (const float*)d_in[4];
    const float* W1_src = (const float*)d_in[5];
    const float* b1_src = (const float*)d_in[6];
    const float* W1_dst = (const float*)d_in[7];
    const float* b1_dst = (const float*)d_in[8];
    const float* attn1 = (const float*)d_in[9];
    const float* W2_src = (const float*)d_in[10];
    const float* b2_src = (const float*)d_in[11];
    const float* W2_dst = (const float*)d_in[12];
    const float* b2_dst = (const float*)d_in[13];
    const float* attn2 = (const float*)d_in[14];
    const float* Wh1 = (const float*)d_in[15];
    const float* bh1 = (const float*)d_in[16];
    const float* Wh2 = (const float*)d_in[17];
    const float* bh2 = (const float*)d_in[18];

    // workspace layout
    float* x = (float*)d_ws;                                          // N*32 f32
    unsigned char* fsh = (unsigned char*)(x + (size_t)N_NODES * 32);  // N*128 fp8
    unsigned short* fdh = (unsigned short*)(fsh + (size_t)N_NODES * 128);  // N*128 bf16
    float* gpart = (float*)(fdh + (size_t)N_NODES * 128);             // 64*32
    int* bh = (int*)(gpart + 64 * 32);                                // NBUCK
    int* bbase = bh + NBUCK;                                          // NBUCK+1
    int* gcur = bbase + NBUCK + 1;                                    // NBUCK
    int* row = gcur + NBUCK;                                          // N+1
    unsigned* stage = (unsigned*)(row + N_NODES + 1);                 // E
    unsigned short* adj = (unsigned short*)(stage + N_EDGES);         // E u16

    const int WB = (N_NODES / NPW + 3) / 4;  // 500 blocks: 4 waves x 25 nodes

    // zero gpart + bucket histogram in one memset (adjacent)
    hipMemsetAsync(gpart, 0, (64 * 32 + NBUCK) * sizeof(int), stream);

    // CSR build (binned)
    k_bhist<<<(N_EDGES + 1023) / 1024, 256, 0, stream>>>(edge_dst, bh);
    k_bscan<<<1, 256, 0, stream>>>(bh, bbase, gcur);
    k_bin<<<(N_EDGES + 4095) / 4096, 256, 0, stream>>>(edge_src, edge_dst, gcur, stage);
    k_csr<<<NBUCK, 256, 0, stream>>>(stage, bbase, row, adj);

    // layer 1 (pipeline-fused embed+proj, low-rank path)
    k_fused1<<<WB, 256, 0, stream>>>(g_feats, W_in, b_in, W1_src, b1_src, W1_dst,
                                     b1_dst, fsh, fdh);
    k_gather<<<N_NODES / 4, 256, 0, stream>>>(fsh, fdh, attn1, row, adj, x, gpart, 0);

    // layer 2 (gather fuses the graph-mean reduction)
    k_proj<<<WB, 256, 0, stream>>>(x, W2_src, b2_src, W2_dst, b2_dst, fsh, fdh);
    k_gather<<<N_NODES / 4, 256, 0, stream>>>(fsh, fdh, attn2, row, adj, x, gpart, 1);

    k_final<<<1, 256, 0, stream>>>(gpart, Wh1, bh1, Wh2, bh2, (float*)d_out);
}